// Round 13
// baseline (2661.903 us; speedup 1.0000x reference)
//
#include <hip/hip_runtime.h>

constexpr int Bb  = 8;
constexpr int HDn = 256;
constexpr int NQn = 300;
constexpr int NCn = 80;
constexpr int NHn = 8;
constexpr int NPn = 4;
constexpr int Sn  = 8400;
constexpr int MQ  = Bb * NQn;   // 2400
constexpr int MS  = Bb * Sn;    // 67200

typedef __attribute__((ext_vector_type(8))) short short8;
typedef __attribute__((ext_vector_type(4))) float floatx4;

__device__ __forceinline__ unsigned short f2bf(float f) {
    unsigned u = __float_as_uint(f);
    unsigned r = u + 0x7FFFu + ((u >> 16) & 1u);
    return (unsigned short)(r >> 16);
}
__device__ __forceinline__ unsigned pack2(float a, float b) {
    return (unsigned)f2bf(a) | ((unsigned)f2bf(b) << 16);
}

// ======= projection (f32): 128 pos x 128 out, 8x8/thread, strided W-cols (conflict-free) =======
__global__ __launch_bounds__(256, 2) void proj_kernel(
    const float* __restrict__ feat, const float* __restrict__ pw,
    const float* __restrict__ bg, const float* __restrict__ bb,
    float* __restrict__ mem,
    int C, int HW, int Wdim, int base)
{
    const int b = blockIdx.z;
    const float* Afeat = feat + (size_t)b * C * HW;
    __shared__ float As[16][128];
    __shared__ float Ws[16][128];
    const int tid = threadIdx.x;
    const int tx = tid & 15, ty = tid >> 4;
    const int p0 = blockIdx.y * 128, o0 = blockIdx.x * 128;
    const int pp4 = (tid & 31) * 4;
    const int cb = tid >> 5;                 // 0..7
    const int wrow = tid >> 1, wk = (tid & 1) * 8;
    float acc[8][8] = {};
    for (int k0 = 0; k0 < C; k0 += 16) {
        float4 va0 = make_float4(0.f, 0.f, 0.f, 0.f), va1 = va0;
        if (p0 + pp4 < HW) {
            va0 = *reinterpret_cast<const float4*>(Afeat + (size_t)(k0 + cb) * HW + p0 + pp4);
            va1 = *reinterpret_cast<const float4*>(Afeat + (size_t)(k0 + cb + 8) * HW + p0 + pp4);
        }
        const float4 w0 = *reinterpret_cast<const float4*>(pw + (size_t)(o0 + wrow) * C + k0 + wk);
        const float4 w1 = *reinterpret_cast<const float4*>(pw + (size_t)(o0 + wrow) * C + k0 + wk + 4);
        __syncthreads();
        As[cb][pp4 + 0] = va0.x; As[cb][pp4 + 1] = va0.y; As[cb][pp4 + 2] = va0.z; As[cb][pp4 + 3] = va0.w;
        As[cb + 8][pp4 + 0] = va1.x; As[cb + 8][pp4 + 1] = va1.y; As[cb + 8][pp4 + 2] = va1.z; As[cb + 8][pp4 + 3] = va1.w;
        Ws[wk + 0][wrow] = w0.x; Ws[wk + 1][wrow] = w0.y; Ws[wk + 2][wrow] = w0.z; Ws[wk + 3][wrow] = w0.w;
        Ws[wk + 4][wrow] = w1.x; Ws[wk + 5][wrow] = w1.y; Ws[wk + 6][wrow] = w1.z; Ws[wk + 7][wrow] = w1.w;
        __syncthreads();
#pragma unroll
        for (int k = 0; k < 16; ++k) {
            const float4 a0 = *reinterpret_cast<const float4*>(&As[k][ty * 8]);
            const float4 a1 = *reinterpret_cast<const float4*>(&As[k][ty * 8 + 4]);
            const float av[8] = {a0.x, a0.y, a0.z, a0.w, a1.x, a1.y, a1.z, a1.w};
            float wv[8];
#pragma unroll
            for (int j = 0; j < 8; ++j) wv[j] = Ws[k][tx + 16 * j];
#pragma unroll
            for (int i = 0; i < 8; ++i)
#pragma unroll
                for (int j = 0; j < 8; ++j)
                    acc[i][j] = fmaf(av[i], wv[j], acc[i][j]);
        }
    }
    float bgv[8], bbv[8];
#pragma unroll
    for (int j = 0; j < 8; ++j) { bgv[j] = bg[o0 + tx + 16 * j]; bbv[j] = bb[o0 + tx + 16 * j]; }
#pragma unroll
    for (int i = 0; i < 8; ++i) {
        const int pp = p0 + ty * 8 + i;
        if (pp >= HW) continue;
        const int yy = pp / Wdim, xx = pp - yy * Wdim;
        const float ax = (xx + 0.5f) / Wdim, ay = (yy + 0.5f) / Wdim;
        const float vm = ((ax > 0.01f) && (ax < 0.99f) && (ay > 0.01f) && (ay < 0.99f)) ? 1.f : 0.f;
        float* op = mem + ((size_t)b * Sn + base + pp) * HDn + o0;
#pragma unroll
        for (int j = 0; j < 8; ++j)
            op[tx + 16 * j] = (acc[i][j] * bgv[j] + bbv[j]) * vm;
    }
}

// ===== f32 eo GEMM + LayerNorm fused; also emits bf16 copy of A (memory) as side output =====
__global__ __launch_bounds__(512) void gemm_eoln(
    const float* __restrict__ A,
    const float* __restrict__ W,
    const float* __restrict__ bias,
    const float* __restrict__ g, const float* __restrict__ bt,
    float* __restrict__ O,
    unsigned short* __restrict__ Abf)
{
    __shared__ float As[16][128];
    __shared__ float Ws[16][256];
    const int tid = threadIdx.x;
    const int tx = tid & 31;
    const int ty = tid >> 5;
    const int m0 = blockIdx.x * 128;
    const int arow = tid >> 2, ak = (tid & 3) * 4;
    const int wrow = tid >> 1, wk = (tid & 1) * 8;
    float acc[8][8] = {};
    for (int k0 = 0; k0 < 256; k0 += 16) {
        const float4 a4 = *reinterpret_cast<const float4*>(A + (size_t)(m0 + arow) * 256 + k0 + ak);
        const float4 w0 = *reinterpret_cast<const float4*>(W + (size_t)wrow * 256 + k0 + wk);
        const float4 w1 = *reinterpret_cast<const float4*>(W + (size_t)wrow * 256 + k0 + wk + 4);
        if (Abf)
            *reinterpret_cast<uint2*>(Abf + (size_t)(m0 + arow) * 256 + k0 + ak) =
                make_uint2(pack2(a4.x, a4.y), pack2(a4.z, a4.w));
        __syncthreads();
        As[ak + 0][arow] = a4.x; As[ak + 1][arow] = a4.y; As[ak + 2][arow] = a4.z; As[ak + 3][arow] = a4.w;
        Ws[wk + 0][wrow] = w0.x; Ws[wk + 1][wrow] = w0.y; Ws[wk + 2][wrow] = w0.z; Ws[wk + 3][wrow] = w0.w;
        Ws[wk + 4][wrow] = w1.x; Ws[wk + 5][wrow] = w1.y; Ws[wk + 6][wrow] = w1.z; Ws[wk + 7][wrow] = w1.w;
        __syncthreads();
#pragma unroll
        for (int k = 0; k < 16; ++k) {
            const float4 a0 = *reinterpret_cast<const float4*>(&As[k][ty * 8]);
            const float4 a1 = *reinterpret_cast<const float4*>(&As[k][ty * 8 + 4]);
            const float4 wv0 = *reinterpret_cast<const float4*>(&Ws[k][tx * 8]);
            const float4 wv1 = *reinterpret_cast<const float4*>(&Ws[k][tx * 8 + 4]);
            const float av[8] = {a0.x, a0.y, a0.z, a0.w, a1.x, a1.y, a1.z, a1.w};
            const float wv[8] = {wv0.x, wv0.y, wv0.z, wv0.w, wv1.x, wv1.y, wv1.z, wv1.w};
#pragma unroll
            for (int i = 0; i < 8; ++i)
#pragma unroll
                for (int j = 0; j < 8; ++j)
                    acc[i][j] = fmaf(av[i], wv[j], acc[i][j]);
        }
    }
    float bv[8], gv[8], btv[8];
#pragma unroll
    for (int j = 0; j < 8; ++j) {
        bv[j] = bias[tx * 8 + j];
        gv[j] = g[tx * 8 + j];
        btv[j] = bt[tx * 8 + j];
    }
#pragma unroll
    for (int i = 0; i < 8; ++i) {
        float s1 = 0.f, s2 = 0.f;
#pragma unroll
        for (int j = 0; j < 8; ++j) {
            const float v = acc[i][j] + bv[j];
            acc[i][j] = v;
            s1 += v; s2 += v * v;
        }
#pragma unroll
        for (int o = 1; o < 32; o <<= 1) {
            s1 += __shfl_xor(s1, o, 64);
            s2 += __shfl_xor(s2, o, 64);
        }
        const float mean = s1 * (1.f / 256.f);
        const float var  = s2 * (1.f / 256.f) - mean * mean;
        const float inv  = rsqrtf(var + 1e-5f);
        float out[8];
#pragma unroll
        for (int j = 0; j < 8; ++j) out[j] = (acc[i][j] - mean) * inv * gv[j] + btv[j];
        float* op = O + (size_t)(m0 + ty * 8 + i) * 256 + tx * 8;
        *reinterpret_cast<float4*>(op) = make_float4(out[0], out[1], out[2], out[3]);
        *reinterpret_cast<float4*>(op + 4) = make_float4(out[4], out[5], out[6], out[7]);
    }
}

// ===== f32 es GEMM + row-max fused; 128-row tile, 8x5/thread =====
__global__ __launch_bounds__(256) void gemm_es(
    const float* __restrict__ A,
    const float* __restrict__ W,
    const float* __restrict__ bias,
    float* __restrict__ smax)
{
    __shared__ float As[16][128];
    __shared__ float Ws[16][80];
    const int tid = threadIdx.x;
    const int tx = tid & 15;
    const int ty = tid >> 4;
    const int m0 = blockIdx.x * 128;
    const int arow = tid >> 1, ak = (tid & 1) * 8;
    float acc[8][5] = {};
    for (int k0 = 0; k0 < 256; k0 += 16) {
        const float4 a0 = *reinterpret_cast<const float4*>(A + (size_t)(m0 + arow) * 256 + k0 + ak);
        const float4 a1 = *reinterpret_cast<const float4*>(A + (size_t)(m0 + arow) * 256 + k0 + ak + 4);
        float4 w0 = make_float4(0.f,0.f,0.f,0.f), w1 = w0;
        const int wrow = tid >> 1, wk = (tid & 1) * 8;
        if (tid < 160) {
            w0 = *reinterpret_cast<const float4*>(W + (size_t)wrow * 256 + k0 + wk);
            w1 = *reinterpret_cast<const float4*>(W + (size_t)wrow * 256 + k0 + wk + 4);
        }
        __syncthreads();
        As[ak + 0][arow] = a0.x; As[ak + 1][arow] = a0.y; As[ak + 2][arow] = a0.z; As[ak + 3][arow] = a0.w;
        As[ak + 4][arow] = a1.x; As[ak + 5][arow] = a1.y; As[ak + 6][arow] = a1.z; As[ak + 7][arow] = a1.w;
        if (tid < 160) {
            Ws[wk + 0][wrow] = w0.x; Ws[wk + 1][wrow] = w0.y; Ws[wk + 2][wrow] = w0.z; Ws[wk + 3][wrow] = w0.w;
            Ws[wk + 4][wrow] = w1.x; Ws[wk + 5][wrow] = w1.y; Ws[wk + 6][wrow] = w1.z; Ws[wk + 7][wrow] = w1.w;
        }
        __syncthreads();
#pragma unroll
        for (int k = 0; k < 16; ++k) {
            const float4 a4 = *reinterpret_cast<const float4*>(&As[k][ty * 8]);
            const float4 a5 = *reinterpret_cast<const float4*>(&As[k][ty * 8 + 4]);
            const float av[8] = {a4.x, a4.y, a4.z, a4.w, a5.x, a5.y, a5.z, a5.w};
            float wv[5];
#pragma unroll
            for (int j = 0; j < 5; ++j) wv[j] = Ws[k][tx * 5 + j];
#pragma unroll
            for (int i = 0; i < 8; ++i)
#pragma unroll
                for (int j = 0; j < 5; ++j)
                    acc[i][j] = fmaf(av[i], wv[j], acc[i][j]);
        }
    }
    float bv[5];
#pragma unroll
    for (int j = 0; j < 5; ++j) bv[j] = bias[tx * 5 + j];
#pragma unroll
    for (int i = 0; i < 8; ++i) {
        float vmax = -3.0e38f;
#pragma unroll
        for (int j = 0; j < 5; ++j) vmax = fmaxf(vmax, acc[i][j] + bv[j]);
#pragma unroll
        for (int o = 1; o < 16; o <<= 1) vmax = fmaxf(vmax, __shfl_xor(vmax, o, 64));
        if (tx == 0) smax[m0 + ty * 8 + i] = vmax;
    }
}

// ===== f32 -> bf16 convert (fallback path only) =====
__global__ void fconv_kernel(const float* __restrict__ in, unsigned short* __restrict__ out, int n4)
{
    const int i = blockIdx.x * 256 + threadIdx.x;
    if (i >= n4) return;
    const float4 v = reinterpret_cast<const float4*>(in)[i];
    reinterpret_cast<uint2*>(out)[i] = make_uint2(pack2(v.x, v.y), pack2(v.z, v.w));
}

// ===== bf16-A MFMA GEMM 128x256: val = membf @ Wval^T + bias, bf16 out =====
__global__ __launch_bounds__(512) void gemm_vbig(
    const unsigned short* __restrict__ A,
    const float* __restrict__ W,
    const float* __restrict__ bias,
    unsigned short* __restrict__ C, int ldc,
    int M)
{
    __shared__ __align__(16) unsigned short As[128 * 40];
    __shared__ __align__(16) unsigned short Bs[256 * 40];
    const int tid = threadIdx.x;
    const int lane = tid & 63, wid = tid >> 6;
    const int wm = wid >> 2, wn = wid & 3;
    const int m0 = blockIdx.x * 128, n0 = blockIdx.y * 256;
    const int arow = tid >> 2, ak = (tid & 3) * 8;
    const int brow = tid >> 1, bk = (tid & 1) * 16;
    const int fs = (lane >> 4) * 8;
    floatx4 acc[4][4];
#pragma unroll
    for (int i = 0; i < 4; ++i)
#pragma unroll
        for (int j = 0; j < 4; ++j) acc[i][j] = (floatx4){0.f, 0.f, 0.f, 0.f};

    for (int k0 = 0; k0 < 256; k0 += 32) {
        const short8 a8 = *reinterpret_cast<const short8*>(A + (size_t)(m0 + arow) * 256 + k0 + ak);
        float wv[16];
        {
            const float* wp = W + (size_t)(n0 + brow) * 256 + k0 + bk;
#pragma unroll
            for (int j = 0; j < 4; ++j) *reinterpret_cast<float4*>(&wv[4 * j]) = *reinterpret_cast<const float4*>(wp + 4 * j);
        }
        __syncthreads();
        *reinterpret_cast<short8*>(&As[arow * 40 + ak]) = a8;
        *reinterpret_cast<uint4*>(&Bs[brow * 40 + bk]) =
            make_uint4(pack2(wv[0], wv[1]), pack2(wv[2], wv[3]), pack2(wv[4], wv[5]), pack2(wv[6], wv[7]));
        *reinterpret_cast<uint4*>(&Bs[brow * 40 + bk + 8]) =
            make_uint4(pack2(wv[8], wv[9]), pack2(wv[10], wv[11]), pack2(wv[12], wv[13]), pack2(wv[14], wv[15]));
        __syncthreads();
        short8 af[4], bf[4];
#pragma unroll
        for (int mi = 0; mi < 4; ++mi)
            af[mi] = *reinterpret_cast<const short8*>(&As[(wm * 64 + mi * 16 + (lane & 15)) * 40 + fs]);
#pragma unroll
        for (int ni = 0; ni < 4; ++ni)
            bf[ni] = *reinterpret_cast<const short8*>(&Bs[(wn * 64 + ni * 16 + (lane & 15)) * 40 + fs]);
#pragma unroll
        for (int mi = 0; mi < 4; ++mi)
#pragma unroll
            for (int ni = 0; ni < 4; ++ni)
                acc[mi][ni] = __builtin_amdgcn_mfma_f32_16x16x32_bf16(af[mi], bf[ni], acc[mi][ni], 0, 0, 0);
    }
#pragma unroll
    for (int mi = 0; mi < 4; ++mi) {
        const int rowb = m0 + wm * 64 + mi * 16 + (lane >> 4) * 4;
#pragma unroll
        for (int ni = 0; ni < 4; ++ni) {
            const int col = n0 + wn * 64 + ni * 16 + (lane & 15);
            const float bv = bias[col];
#pragma unroll
            for (int r = 0; r < 4; ++r)
                C[(size_t)(rowb + r) * ldc + col] = f2bf(acc[mi][ni][r] + bv);
        }
    }
}

// ===== SMALL bf16 GEMM 64x64, full-K LDS staging; n-tiles on blockIdx.x =====
template <int ACT>
__global__ __launch_bounds__(256) void gemm_sm(
    const float* __restrict__ A, const float* __restrict__ A2, int a2_nlim, int lda,
    const float* __restrict__ W, int ldw,
    const float* __restrict__ bias,
    float* __restrict__ C, int ldc,
    int M, int N, int K)
{
    constexpr int LD = 264;
    __shared__ __align__(16) unsigned short As[64 * LD];
    __shared__ __align__(16) unsigned short Bs[64 * LD];
    const int tid = threadIdx.x;
    const int lane = tid & 63, wid = tid >> 6;
    const int wr = wid >> 1, wc = wid & 1;
    const int m0 = blockIdx.y * 64, n0 = blockIdx.x * 64;
    const float* A2e = (A2 && n0 < a2_nlim) ? A2 : nullptr;
    const int srow = tid >> 2;
    const int cb   = (tid & 3) * 16;
    const int fs = (lane >> 4) * 8;
    floatx4 acc[2][2];
#pragma unroll
    for (int i = 0; i < 2; ++i)
#pragma unroll
        for (int j = 0; j < 2; ++j) acc[i][j] = (floatx4){0.f, 0.f, 0.f, 0.f};

    for (int kc = 0; kc < K; kc += 256) {
        if (kc) __syncthreads();
        {
            const bool mok = (m0 + srow < M);
            const float* ap = A + (size_t)(m0 + srow) * lda + kc;
            const float* ap2 = A2e ? A2e + (size_t)(m0 + srow) * lda + kc : nullptr;
#pragma unroll
            for (int c = 0; c < 4; ++c) {
                float4 v[4];
#pragma unroll
                for (int j = 0; j < 4; ++j) {
                    v[j] = make_float4(0.f, 0.f, 0.f, 0.f);
                    if (mok) {
                        v[j] = *reinterpret_cast<const float4*>(ap + cb + c * 64 + j * 4);
                        if (ap2) {
                            const float4 v2 = *reinterpret_cast<const float4*>(ap2 + cb + c * 64 + j * 4);
                            v[j].x += v2.x; v[j].y += v2.y; v[j].z += v2.z; v[j].w += v2.w;
                        }
                    }
                }
#pragma unroll
                for (int j = 0; j < 4; ++j)
                    *reinterpret_cast<uint2*>(&As[srow * LD + cb + c * 64 + j * 4]) =
                        make_uint2(pack2(v[j].x, v[j].y), pack2(v[j].z, v[j].w));
            }
        }
        {
            const bool nok = (n0 + srow < N);
            const float* wp = W + (size_t)(n0 + srow) * ldw + kc;
#pragma unroll
            for (int c = 0; c < 4; ++c) {
                float4 v[4];
#pragma unroll
                for (int j = 0; j < 4; ++j) {
                    v[j] = make_float4(0.f, 0.f, 0.f, 0.f);
                    if (nok) v[j] = *reinterpret_cast<const float4*>(wp + cb + c * 64 + j * 4);
                }
#pragma unroll
                for (int j = 0; j < 4; ++j)
                    *reinterpret_cast<uint2*>(&Bs[srow * LD + cb + c * 64 + j * 4]) =
                        make_uint2(pack2(v[j].x, v[j].y), pack2(v[j].z, v[j].w));
            }
        }
        __syncthreads();
#pragma unroll
        for (int ks = 0; ks < 8; ++ks) {
            short8 af[2], bf[2];
#pragma unroll
            for (int mi = 0; mi < 2; ++mi)
                af[mi] = *reinterpret_cast<const short8*>(&As[(wr * 32 + mi * 16 + (lane & 15)) * LD + ks * 32 + fs]);
#pragma unroll
            for (int ni = 0; ni < 2; ++ni)
                bf[ni] = *reinterpret_cast<const short8*>(&Bs[(wc * 32 + ni * 16 + (lane & 15)) * LD + ks * 32 + fs]);
#pragma unroll
            for (int mi = 0; mi < 2; ++mi)
#pragma unroll
                for (int ni = 0; ni < 2; ++ni)
                    acc[mi][ni] = __builtin_amdgcn_mfma_f32_16x16x32_bf16(af[mi], bf[ni], acc[mi][ni], 0, 0, 0);
        }
    }
#pragma unroll
    for (int mi = 0; mi < 2; ++mi) {
        const int rowb = m0 + wr * 32 + mi * 16 + (lane >> 4) * 4;
#pragma unroll
        for (int ni = 0; ni < 2; ++ni) {
            const int col = n0 + wc * 32 + ni * 16 + (lane & 15);
            if (col >= N) continue;
            const float bv = bias[col];
#pragma unroll
            for (int r = 0; r < 4; ++r) {
                const int row = rowb + r;
                if (row >= M) continue;
                float v = acc[mi][ni][r] + bv;
                if (ACT == 1) v = fmaxf(v, 0.f);
                C[(size_t)row * ldc + col] = v;
            }
        }
    }
}

// ============== qpos: C = (relu(ref @ w1^T + b1)) @ w2^T + b2 ==============
__global__ __launch_bounds__(256) void gemm_qpos(
    const float* __restrict__ ref, const float* __restrict__ w1, const float* __restrict__ b1,
    const float* __restrict__ W2, const float* __restrict__ b2,
    float* __restrict__ C, int M)
{
    __shared__ __align__(16) unsigned short As_h[128 * 40];
    __shared__ __align__(16) unsigned short Bs_h[128 * 40];
    __shared__ float w1s[512 * 4];
    __shared__ float b1s[512];
    const int tid = threadIdx.x;
    const int lane = tid & 63, wid = tid >> 6;
    const int wm = wid >> 1, wn = wid & 1;
    const int m0 = blockIdx.x * 128, n0 = blockIdx.y * 128;
    const int srow = tid >> 1, skoff = (tid & 1) * 16;
    const int fs = (lane >> 4) * 8;
    for (int i = tid; i < 512 * 4; i += 256) w1s[i] = w1[i];
    for (int i = tid; i < 512; i += 256) b1s[i] = b1[i];
    float rv0 = 0.f, rv1 = 0.f, rv2 = 0.f, rv3 = 0.f;
    if (m0 + srow < M) {
        const float* rp = ref + (size_t)(m0 + srow) * 4;
        rv0 = rp[0]; rv1 = rp[1]; rv2 = rp[2]; rv3 = rp[3];
    }
    floatx4 acc[4][4];
#pragma unroll
    for (int i = 0; i < 4; ++i)
#pragma unroll
        for (int j = 0; j < 4; ++j) acc[i][j] = (floatx4){0.f, 0.f, 0.f, 0.f};
    __syncthreads();

    for (int k0 = 0; k0 < 512; k0 += 32) {
        float av[16], wv[16];
#pragma unroll
        for (int j = 0; j < 16; ++j) {
            const int k = k0 + skoff + j;
            const float v = b1s[k] + rv0 * w1s[k * 4] + rv1 * w1s[k * 4 + 1] + rv2 * w1s[k * 4 + 2] + rv3 * w1s[k * 4 + 3];
            av[j] = fmaxf(v, 0.f);
            wv[j] = 0.f;
        }
        if (n0 + srow < 256) {
            const float* wp = W2 + (size_t)(n0 + srow) * 512 + k0 + skoff;
#pragma unroll
            for (int j = 0; j < 4; ++j) *reinterpret_cast<float4*>(&wv[4 * j]) = *reinterpret_cast<const float4*>(wp + 4 * j);
        }
        __syncthreads();
        *reinterpret_cast<uint4*>(&As_h[srow * 40 + skoff]) =
            make_uint4(pack2(av[0], av[1]), pack2(av[2], av[3]), pack2(av[4], av[5]), pack2(av[6], av[7]));
        *reinterpret_cast<uint4*>(&As_h[srow * 40 + skoff + 8]) =
            make_uint4(pack2(av[8], av[9]), pack2(av[10], av[11]), pack2(av[12], av[13]), pack2(av[14], av[15]));
        *reinterpret_cast<uint4*>(&Bs_h[srow * 40 + skoff]) =
            make_uint4(pack2(wv[0], wv[1]), pack2(wv[2], wv[3]), pack2(wv[4], wv[5]), pack2(wv[6], wv[7]));
        *reinterpret_cast<uint4*>(&Bs_h[srow * 40 + skoff + 8]) =
            make_uint4(pack2(wv[8], wv[9]), pack2(wv[10], wv[11]), pack2(wv[12], wv[13]), pack2(wv[14], wv[15]));
        __syncthreads();
        short8 af[4], bff[4];
#pragma unroll
        for (int mi = 0; mi < 4; ++mi) {
            const int r = wm * 64 + mi * 16 + (lane & 15);
            af[mi] = *reinterpret_cast<const short8*>(&As_h[r * 40 + fs]);
        }
#pragma unroll
        for (int ni = 0; ni < 4; ++ni) {
            const int r = wn * 64 + ni * 16 + (lane & 15);
            bff[ni] = *reinterpret_cast<const short8*>(&Bs_h[r * 40 + fs]);
        }
#pragma unroll
        for (int mi = 0; mi < 4; ++mi)
#pragma unroll
            for (int ni = 0; ni < 4; ++ni)
                acc[mi][ni] = __builtin_amdgcn_mfma_f32_16x16x32_bf16(af[mi], bff[ni], acc[mi][ni], 0, 0, 0);
    }
#pragma unroll
    for (int mi = 0; mi < 4; ++mi) {
        const int rowb = m0 + wm * 64 + mi * 16 + (lane >> 4) * 4;
#pragma unroll
        for (int ni = 0; ni < 4; ++ni) {
            const int col = n0 + wn * 64 + ni * 16 + (lane & 15);
            const float bv = b2[col];
#pragma unroll
            for (int r = 0; r < 4; ++r) {
                const int row = rowb + r;
                if (row >= M) continue;
                C[(size_t)row * HDn + col] = acc[mi][ni][r] + bv;
            }
        }
    }
}

// ================= LayerNorm over rows of 256 with residual =================
__global__ __launch_bounds__(256) void ln_kernel(
    const float* __restrict__ X, const float* __restrict__ R,
    const float* __restrict__ g, const float* __restrict__ bta,
    float* __restrict__ O)
{
    const int m = blockIdx.x;
    const int t = threadIdx.x;
    float v = X[(size_t)m * HDn + t] + R[(size_t)m * HDn + t];
    float s1 = v, s2 = v * v;
#pragma unroll
    for (int o = 32; o > 0; o >>= 1) {
        s1 += __shfl_down(s1, o, 64);
        s2 += __shfl_down(s2, o, 64);
    }
    __shared__ float a1[4], a2[4];
    if ((t & 63) == 0) { a1[t >> 6] = s1; a2[t >> 6] = s2; }
    __syncthreads();
    const float S1 = a1[0] + a1[1] + a1[2] + a1[3];
    const float S2 = a2[0] + a2[1] + a2[2] + a2[3];
    const float mean = S1 * (1.f / HDn);
    const float var  = S2 * (1.f / HDn) - mean * mean;
    const float inv  = rsqrtf(var + 1e-5f);
    O[(size_t)m * HDn + t] = (v - mean) * inv * g[t] + bta[t];
}

// ===== top-300 per batch via MSB radix select =====
__global__ __launch_bounds__(256) void topk_kernel(const float* __restrict__ smax, int* __restrict__ topi)
{
    const int b = blockIdx.x, t = threadIdx.x;
    __shared__ float vals[Sn];
    __shared__ int hist[256];
    __shared__ unsigned long long sel[NQn];
    __shared__ unsigned long long s_prefix;
    __shared__ int s_need;
    __shared__ int s_cnt;
    for (int i = t; i < Sn; i += 256) vals[i] = smax[(size_t)b * Sn + i];
    if (t == 0) { s_prefix = 0ULL; s_need = NQn; s_cnt = 0; }
    __syncthreads();

    for (int shift = 56; shift >= 0; shift -= 8) {
        if (t < 256) hist[t] = 0;
        __syncthreads();
        const unsigned long long prefix = s_prefix;
        const unsigned long long mask = (shift == 56) ? 0ULL : (~0ULL << (shift + 8));
        for (int i = t; i < Sn; i += 256) {
            unsigned uk = __float_as_uint(vals[i]);
            uk = (uk & 0x80000000u) ? ~uk : (uk | 0x80000000u);
            const unsigned long long key = ((unsigned long long)uk << 32) | (unsigned)(Sn - i);
            if ((key & mask) == prefix)
                atomicAdd(&hist[(int)((key >> shift) & 255)], 1);
        }
        __syncthreads();
        if (t == 0) {
            int need = s_need, accum = 0, v = 255;
            for (; v >= 0; --v) {
                const int c = hist[v];
                if (accum + c >= need) break;
                accum += c;
            }
            s_prefix = s_prefix | ((unsigned long long)(unsigned)v << shift);
            s_need = need - accum;
        }
        __syncthreads();
    }
    const unsigned long long thresh = s_prefix;
    for (int i = t; i < Sn; i += 256) {
        unsigned uk = __float_as_uint(vals[i]);
        uk = (uk & 0x80000000u) ? ~uk : (uk | 0x80000000u);
        const unsigned long long key = ((unsigned long long)uk << 32) | (unsigned)(Sn - i);
        if (key >= thresh) {
            const int pos = atomicAdd(&s_cnt, 1);
            if (pos < NQn) sel[pos] = key;
        }
    }
    __syncthreads();
    for (int j = t; j < NQn; j += 256) {
        const unsigned long long kj = sel[j];
        int rank = 0;
        for (int i = 0; i < NQn; ++i) rank += (sel[i] > kj) ? 1 : 0;
        topi[b * NQn + rank] = Sn - (int)(kj & 0xFFFFFFFFULL);
    }
}

// ================= gather selected rows =================
__global__ __launch_bounds__(256) void gather_kernel(const float* __restrict__ src, const int* __restrict__ topi,
                                                     float* __restrict__ dst)
{
    const int m = blockIdx.x;
    const int b = m / NQn;
    const int s = topi[m];
    dst[(size_t)m * HDn + threadIdx.x] = src[((size_t)b * Sn + s) * HDn + threadIdx.x];
}

// ================= anchors =================
__device__ __forceinline__ void anchor_of(int s, float a[4])
{
    int lvl, p, w;
    if (s < 6400)      { lvl = 0; p = s;        w = 80; }
    else if (s < 8000) { lvl = 1; p = s - 6400; w = 40; }
    else               { lvl = 2; p = s - 8000; w = 20; }
    const int y = p / w, x = p - y * w;
    const float ax = (x + 0.5f) / w, ay = (y + 0.5f) / w;
    const float awh = 0.05f * (float)(1 << lvl);
    const bool valid = (ax > 0.01f) && (ax < 0.99f) && (ay > 0.01f) && (ay < 0.99f);
    if (valid) {
        a[0] = logf(ax / (1.f - ax));
        a[1] = logf(ay / (1.f - ay));
        const float lw = logf(awh / (1.f - awh));
        a[2] = lw; a[3] = lw;
    } else {
        a[0] = a[1] = a[2] = a[3] = 1e6f;
    }
}

// ===== fused N=4 head + ref update; optionally mirrors ref into out[84-stride] rows =====
template <int MODE>
__global__ __launch_bounds__(256) void head4_kernel(
    const float* __restrict__ A, const float* __restrict__ W, const float* __restrict__ bias,
    const int* __restrict__ topi, float* __restrict__ ref, float* __restrict__ outref)
{
    const int wv = threadIdx.x >> 6, lane = threadIdx.x & 63;
    const int m = blockIdx.x * 4 + wv;
    if (m >= MQ) return;
    const float4 a = *reinterpret_cast<const float4*>(A + (size_t)m * HDn + lane * 4);
    float d[4];
#pragma unroll
    for (int c = 0; c < 4; ++c) {
        const float4 w = *reinterpret_cast<const float4*>(W + c * HDn + lane * 4);
        float p = a.x * w.x + a.y * w.y + a.z * w.z + a.w * w.w;
#pragma unroll
        for (int o = 32; o > 0; o >>= 1) p += __shfl_xor(p, o, 64);
        d[c] = p;
    }
    if (lane == 0) {
        float base[4];
        if (MODE == 0) {
            anchor_of(topi[m], base);
        } else {
#pragma unroll
            for (int c = 0; c < 4; ++c) {
                float x = ref[m * 4 + c];
                x = fminf(fmaxf(x, 0.f), 1.f);
                base[c] = logf(fmaxf(x, 1e-5f) / fmaxf(1.f - x, 1e-5f));
            }
        }
#pragma unroll
        for (int c = 0; c < 4; ++c) {
            const float x = d[c] + bias[c] + base[c];
            const float r = 1.f / (1.f + expf(-x));
            ref[m * 4 + c] = r;
            if (outref) outref[(size_t)m * 84 + 80 + c] = r;
        }
    }
}

// ===== fused MHA: q-split across blocks (z), k-split within block =====
__global__ __launch_bounds__(320) void mha_kernel(const float* __restrict__ QKV, float* __restrict__ O)
{
    const int h = blockIdx.x, b = blockIdx.y, qs = blockIdx.z;
    __shared__ float Ks[NQn][32];
    __shared__ float Vs[NQn][32];
    __shared__ float Om[152][32];
    __shared__ float Mm[152];
    __shared__ float Lm[152];
    const int t = threadIdx.x;
    for (int i = t; i < NQn * 32; i += 320) {
        const int kk = i >> 5, d = i & 31;
        const size_t src = ((size_t)(b * NQn + kk)) * 768 + h * 32 + d;
        Ks[kk][d] = QKV[src + 256];
        Vs[kk][d] = QKV[src + 512];
    }
    __syncthreads();
    const int half = (t >= 160) ? 1 : 0;
    const int qloc = half ? (t - 160) : t;
    const int q = qs * 150 + qloc;
    float m = -1e30f, l = 0.f;
    float o[32];
    if (qloc < 150) {
        float qv[32];
        const float* qp = QKV + ((size_t)(b * NQn + q)) * 768 + h * 32;
#pragma unroll
        for (int d = 0; d < 32; ++d) qv[d] = qp[d] * 0.17677669529663687f;
#pragma unroll
        for (int d = 0; d < 32; ++d) o[d] = 0.f;
        const int k0 = half * 150, k1 = k0 + 150;
        for (int kk = k0; kk < k1; ++kk) {
            float s0 = 0.f, s1 = 0.f, s2 = 0.f, s3 = 0.f;
#pragma unroll
            for (int d = 0; d < 32; d += 4) {
                s0 = fmaf(qv[d + 0], Ks[kk][d + 0], s0);
                s1 = fmaf(qv[d + 1], Ks[kk][d + 1], s1);
                s2 = fmaf(qv[d + 2], Ks[kk][d + 2], s2);
                s3 = fmaf(qv[d + 3], Ks[kk][d + 3], s3);
            }
            const float s = (s0 + s1) + (s2 + s3);
            if (s > m + 8.f) {
                const float cf = __expf(m - s);
                m = s;
                l *= cf;
#pragma unroll
                for (int d = 0; d < 32; ++d) o[d] *= cf;
            }
            const float pv = __expf(s - m);
            l += pv;
#pragma unroll
            for (int d = 0; d < 32; ++d) o[d] = fmaf(pv, Vs[kk][d], o[d]);
        }
        if (half) {
            Mm[qloc] = m; Lm[qloc] = l;
#pragma unroll
            for (int d = 0; d < 32; ++d) Om[qloc][d] = o[d];
        }
    }
    __syncthreads();
    if (!half && qloc < 150) {
        const float m2 = Mm[qloc], l2 = Lm[qloc];
        const float mm = fmaxf(m, m2);
        const float c1 = __expf(m - mm), c2 = __expf(m2 - mm);
        const float L = l * c1 + l2 * c2;
        const float inv = 1.f / L;
        float* op = O + ((size_t)(b * NQn + q)) * HDn + h * 32;
#pragma unroll
        for (int d = 0; d < 32; ++d) op[d] = (o[d] * c1 + Om[qloc][d] * c2) * inv;
    }
}

// ====== concat off/aw weights+biases once ======
__global__ void concat_oaw(const float* __restrict__ offw, const float* __restrict__ offbias,
                           const float* __restrict__ aww, const float* __restrict__ awbias,
                           float* __restrict__ cw, float* __restrict__ cb)
{
    const int idx = blockIdx.x * 256 + threadIdx.x;
    const int TW = 6 * 288 * 256;
    if (idx < TW) {
        const int i = idx / (288 * 256);
        const int r = (idx / 256) % 288;
        const int c = idx & 255;
        cw[idx] = (r < 192) ? offw[((size_t)i * 192 + r) * 256 + c]
                            : aww[((size_t)i * 96 + (r - 192)) * 256 + c];
    } else if (idx < TW + 6 * 288) {
        const int j = idx - TW;
        const int i = j / 288, r = j % 288;
        cb[j] = (r < 192) ? offbias[i * 192 + r] : awbias[i * 96 + (r - 192)];
    }
}

// ============ deformable attention sampling (bf16 value tensor), softmax12 fused ============
__global__ __launch_bounds__(256) void msda_kernel(const unsigned short* __restrict__ val, int ldv,
                                                   const float* __restrict__ oaw,
                                                   const float* __restrict__ ref,
                                                   float* __restrict__ out)
{
    const int mq = blockIdx.x;
    const int b = mq / NQn;
    const int t = threadIdx.x;
    const int h = t >> 5, d = t & 31;
    __shared__ float s_ref[4];
    __shared__ float s_aw[96];
    __shared__ float s_off[192];
    if (t < 4) s_ref[t] = ref[mq * 4 + t];
    if (t < 96) s_aw[t] = oaw[(size_t)mq * 288 + 192 + t];
    if (t < 192) s_off[t] = oaw[(size_t)mq * 288 + t];
    __syncthreads();
    if (t < 8) {
        float* p = s_aw + t * 12;
        float mx = -1e30f;
#pragma unroll
        for (int i = 0; i < 12; ++i) mx = fmaxf(mx, p[i]);
        float e[12];
        float s = 0.f;
#pragma unroll
        for (int i = 0; i < 12; ++i) { e[i] = expf(p[i] - mx); s += e[i]; }
        const float inv = 1.f / s;
#pragma unroll
        for (int i = 0; i < 12; ++i) p[i] = e[i] * inv;
    }
    __syncthreads();
    const int Wl[3] = {80, 40, 20};
    const int base[3] = {0, 6400, 8000};
    float acc = 0.f;
#pragma unroll
    for (int l = 0; l < 3; ++l) {
        const int W = Wl[l];
        const unsigned short* vb = val + ((size_t)b * Sn + base[l]) * ldv + h * 32 + d;
#pragma unroll
        for (int p = 0; p < 4; ++p) {
            const float ox = s_off[((h * 3 + l) * 4 + p) * 2 + 0];
            const float oy = s_off[((h * 3 + l) * 4 + p) * 2 + 1];
            const float locx = s_ref[0] + ox * (1.f / NPn) * s_ref[2] * 0.5f;
            const float locy = s_ref[1] + oy * (1.f / NPn) * s_ref[3] * 0.5f;
            const float x = locx * W - 0.5f;
            const float y = locy * W - 0.5f;
            const float x0f = floorf(x), y0f = floorf(y);
            const float lx = x - x0f, ly = y - y0f;
            const int x0 = (int)x0f, y0 = (int)y0f;
            const float a = s_aw[h * 12 + l * 4 + p];
            const float wts[4] = {(1.f - lx) * (1.f - ly), lx * (1.f - ly), (1.f - lx) * ly, lx * ly};
            float sum = 0.f;
#pragma unroll
            for (int c2 = 0; c2 < 4; ++c2) {
                const int xi = x0 + (c2 & 1);
                const int yi = y0 + (c2 >> 1);
                const bool ok = (xi >= 0) && (xi < W) && (yi >= 0) && (yi < W);
                const int xc = min(max(xi, 0), W - 1);
                const int yc = min(max(yi, 0), W - 1);
                const float v = __uint_as_float((unsigned)vb[(size_t)(yc * W + xc) * ldv] << 16);
                sum = fmaf(wts[c2], ok ? v : 0.f, sum);
            }
            acc = fmaf(a, sum, acc);
        }
    }
    out[(size_t)mq * HDn + t] = acc;
}

// =======================================================================================
extern "C" void kernel_launch(void* const* d_in, const int* in_sizes, int n_in,
                              void* d_out, int out_size, void* d_ws, size_t ws_size,
                              hipStream_t stream)
{
    (void)in_sizes; (void)n_in; (void)out_size;
    const float* feat0 = (const float*)d_in[0];
    const float* pw0   = (const float*)d_in[1];
    const float* bg0   = (const float*)d_in[2];
    const float* bb0   = (const float*)d_in[3];
    const float* feat1 = (const float*)d_in[4];
    const float* pw1   = (const float*)d_in[5];
    const float* bg1   = (const float*)d_in[6];
    const float* bb1   = (const float*)d_in[7];
    const float* feat2 = (const float*)d_in[8];
    const float* pw2   = (const float*)d_in[9];
    const float* bg2   = (const float*)d_in[10];
    const float* bb2   = (const float*)d_in[11];
    const float* eo_w  = (const float*)d_in[12];
    const float* eo_b  = (const float*)d_in[13];
    const float* eln_g = (const float*)d_in[14];
    const float* eln_b = (const float*)d_in[15];
    const float* es_w  = (const float*)d_in[16];
    const float* es_b  = (const float*)d_in[17];
    const float* eb_w1 = (const float*)d_in[18];
    const float* eb_b1 = (const float*)d_in[19];
    const float* eb_w2 = (const float*)d_in[20];
    const float* eb_b2 = (const float*)d_in[21];
    const float* eb_w3 = (const float*)d_in[22];
    const float* eb_b3 = (const float*)d_in[23];
    const float* qp_w1 = (const float*)d_in[24];
    const float* qp_b1 = (const float*)d_in[25];
    const float* qp_w2 = (const float*)d_in[26];
    const float* qp_b2 = (const float*)d_in[27];
    const float* d_qkv_w = (const float*)d_in[28];
    const float* d_qkv_b = (const float*)d_in[29];
    const float* d_ao_w  = (const float*)d_in[30];
    const float* d_ao_b  = (const float*)d_in[31];
    const float* d_ln1_g = (const float*)d_in[32];
    const float* d_ln1_b = (const float*)d_in[33];
    const float* d_off_w = (const float*)d_in[34];
    const float* d_off_b = (const float*)d_in[35];
    const float* d_aw_w  = (const float*)d_in[36];
    const float* d_aw_b  = (const float*)d_in[37];
    const float* d_val_w = (const float*)d_in[38];
    const float* d_val_b = (const float*)d_in[39];
    const float* d_out_w = (const float*)d_in[40];
    const float* d_out_b = (const float*)d_in[41];
    const float* d_ln2_g = (const float*)d_in[42];
    const float* d_ln2_b = (const float*)d_in[43];
    const float* d_f1_w  = (const float*)d_in[44];
    const float* d_f1_b  = (const float*)d_in[45];
    const float* d_f2_w  = (const float*)d_in[46];
    const float* d_f2_b  = (const float*)d_in[47];
    const float* d_ln3_g = (const float*)d_in[48];
    const float* d_ln3_b = (const float*)d_in[49];
    const float* d_sc_w  = (const float*)d_in[50];
    const float* d_sc_b  = (const float*)d_in[51];
    const float* d_bb_w1 = (const float*)d_in[52];
    const float* d_bb_b1 = (const float*)d_in[53];
    const float* d_bb_w2 = (const float*)d_in[54];
    const float* d_bb_b2 = (const float*)d_in[55];
    const float* d_bb_w3 = (const float*)d_in[56];
    const float* d_bb_b3 = (const float*)d_in[57];

    float* ws = (float*)d_ws;
    size_t off = 0;
    auto alloc = [&](size_t n) { float* p = ws + off; off += (n + 63) & ~(size_t)63; return p; };
    float* memory = alloc((size_t)MS * HDn);
    float* om     = alloc((size_t)MS * HDn);
    float* smaxb  = alloc((size_t)MS);
    int*   topi   = (int*)alloc((size_t)MQ);
    float* tgt    = alloc((size_t)MQ * HDn);
    float* refb   = alloc((size_t)MQ * 4);
    float* qpos   = alloc((size_t)MQ * HDn);
    float* qkvb   = alloc((size_t)MQ * 768);
    float* atto   = alloc((size_t)MQ * HDn);
    float* abuf   = alloc((size_t)MQ * HDn);
    float* oawb   = alloc((size_t)MQ * 288);
    float* msd    = alloc((size_t)MQ * HDn);
    float* ffb    = alloc((size_t)MQ * 1024);
    float* qb     = alloc((size_t)MQ * HDn);
    float* kb     = alloc((size_t)MQ * HDn);
    float* cw     = alloc((size_t)6 * 288 * 256);
    float* cb     = alloc((size_t)6 * 288);
    const size_t VALBIG_FLOATS = (size_t)MS * 768;   // [MS][1536] bf16
    const size_t MEMBF_FLOATS  = (size_t)MS * 128;   // [MS][256] bf16
    unsigned short* valbig = nullptr;
    unsigned short* membf  = nullptr;
    if ((off + VALBIG_FLOATS + MEMBF_FLOATS + 128) * sizeof(float) <= ws_size) {
        valbig = (unsigned short*)alloc(VALBIG_FLOATS);
        membf  = (unsigned short*)alloc(MEMBF_FLOATS);
    }
    const bool batched = (valbig != nullptr);
    unsigned short* ombf = (unsigned short*)om;   // fallback path scratch
    float* outp = (float*)d_out;

    // ---- weight concat for merged off+aw GEMM ----
    concat_oaw<<<(6 * 288 * 256 + 6 * 288 + 255) / 256, 256, 0, stream>>>(d_off_w, d_off_b, d_aw_w, d_aw_b, cw, cb);

    // ---- stage 1: projection (f32 — selection-critical score path) ----
    proj_kernel<<<dim3(2, 50, 8), 256, 0, stream>>>(feat0, pw0, bg0, bb0, memory, 512, 6400, 80, 0);
    proj_kernel<<<dim3(2, 13, 8), 256, 0, stream>>>(feat1, pw1, bg1, bb1, memory, 1024, 1600, 40, 6400);
    proj_kernel<<<dim3(2, 4, 8), 256, 0, stream>>>(feat2, pw2, bg2, bb2, memory, 2048, 400, 20, 8000);

    // ---- stage 2: encoder head (f32, fused); eoln also emits bf16(memory) ----
    gemm_eoln<<<525, 512, 0, stream>>>(memory, eo_w, eo_b, eln_g, eln_b, om, batched ? membf : nullptr);
    gemm_es<<<525, 256, 0, stream>>>(om, es_w, es_b, smaxb);
    topk_kernel<<<Bb, 256, 0, stream>>>(smaxb, topi);
    gather_kernel<<<MQ, 256, 0, stream>>>(om, topi, tgt);

    // ---- ref init ----
    gemm_sm<1><<<dim3(4, 38), 256, 0, stream>>>(tgt, nullptr, 0, HDn, eb_w1, HDn, eb_b1, qb, HDn, MQ, HDn, HDn);
    gemm_sm<1><<<dim3(4, 38), 256, 0, stream>>>(qb, nullptr, 0, HDn, eb_w2, HDn, eb_b2, kb, HDn, MQ, HDn, HDn);
    head4_kernel<0><<<600, 256, 0, stream>>>(kb, eb_w3, eb_b3, topi, refb, nullptr);

    // ---- all 6 layers' value projections: one wide bf16 GEMM on membf ----
    if (batched)
        gemm_vbig<<<dim3(525, 6), 512, 0, stream>>>(membf, d_val_w, d_val_b, valbig, 1536, MS);

    // ---- decoder layers ----
    for (int i = 0; i < 6; ++i) {
        const float* wqkv = d_qkv_w + (size_t)i * 768 * 256;
        const float* bqkv = d_qkv_b + (size_t)i * 768;
        gemm_qpos<<<dim3(19, 2), 256, 0, stream>>>(refb, qp_w1, qp_b1, qp_w2, qp_b2, qpos, MQ);
        gemm_sm<0><<<dim3(12, 38), 256, 0, stream>>>(tgt, qpos, 512, HDn, wqkv, HDn, bqkv, qkvb, 768, MQ, 768, HDn);
        mha_kernel<<<dim3(NHn, Bb, 2), 320, 0, stream>>>(qkvb, atto);
        gemm_sm<0><<<dim3(4, 38), 256, 0, stream>>>(atto, nullptr, 0, HDn, d_ao_w + (size_t)i * 65536, HDn,
                                                    d_ao_b + (size_t)i * 256, abuf, HDn, MQ, HDn, HDn);
        ln_kernel<<<MQ, 256, 0, stream>>>(abuf, tgt, d_ln1_g + (size_t)i * 256, d_ln1_b + (size_t)i * 256, tgt);
        gemm_sm<0><<<dim3(5, 38), 256, 0, stream>>>(tgt, qpos, 1 << 30, HDn, cw + (size_t)i * 288 * 256, HDn,
                                                    cb + (size_t)i * 288, oawb, 288, MQ, 288, HDn);
        const unsigned short* valptr;
        int ldv;
        if (batched) { valptr = valbig + (size_t)i * 256; ldv = 1536; }
        else {
            fconv_kernel<<<(MS * HDn / 4 + 255) / 256, 256, 0, stream>>>(memory, (unsigned short*)ffb, MS * HDn / 4);
            gemm_vbig<<<dim3(525, 1), 512, 0, stream>>>((unsigned short*)ffb, d_val_w + (size_t)i * 65536,
                                                        d_val_b + (size_t)i * 256, ombf, 256, MS);
            valptr = ombf; ldv = 256;
        }
        msda_kernel<<<MQ, 256, 0, stream>>>(valptr, ldv, oawb, refb, msd);
        gemm_sm<0><<<dim3(4, 38), 256, 0, stream>>>(msd, nullptr, 0, HDn, d_out_w + (size_t)i * 65536, HDn,
                                                    d_out_b + (size_t)i * 256, abuf, HDn, MQ, HDn, HDn);
        ln_kernel<<<MQ, 256, 0, stream>>>(abuf, tgt, d_ln2_g + (size_t)i * 256, d_ln2_b + (size_t)i * 256, tgt);
        gemm_sm<1><<<dim3(16, 38), 256, 0, stream>>>(tgt, nullptr, 0, HDn, d_f1_w + (size_t)i * 1024 * 256, HDn,
                                                     d_f1_b + (size_t)i * 1024, ffb, 1024, MQ, 1024, HDn);
        gemm_sm<0><<<dim3(4, 38), 256, 0, stream>>>(ffb, nullptr, 0, 1024, d_f2_w + (size_t)i * 256 * 1024, 1024,
                                                    d_f2_b + (size_t)i * 256, abuf, HDn, MQ, HDn, 1024);
        ln_kernel<<<MQ, 256, 0, stream>>>(abuf, tgt, d_ln3_g + (size_t)i * 256, d_ln3_b + (size_t)i * 256, tgt);
        gemm_sm<1><<<dim3(4, 38), 256, 0, stream>>>(tgt, nullptr, 0, HDn, d_bb_w1 + (size_t)i * 65536, HDn,
                                                    d_bb_b1 + (size_t)i * 256, qb, HDn, MQ, HDn, HDn);
        gemm_sm<1><<<dim3(4, 38), 256, 0, stream>>>(qb, nullptr, 0, HDn, d_bb_w2 + (size_t)i * 65536, HDn,
                                                    d_bb_b2 + (size_t)i * 256, kb, HDn, MQ, HDn, HDn);
        head4_kernel<1><<<600, 256, 0, stream>>>(kb, d_bb_w3 + (size_t)i * 1024, d_bb_b3 + (size_t)i * 4,
                                                 nullptr, refb, (i == 5) ? outp : nullptr);
    }

    // ---- final logits head into d_out: [logits(80) | ref(4)] per (b,q) ----
    gemm_sm<0><<<dim3(2, 38), 256, 0, stream>>>(tgt, nullptr, 0, HDn, d_sc_w + (size_t)5 * 80 * 256, HDn,
                                                d_sc_b + (size_t)5 * 80, outp, 84, MQ, NCn, HDn);
}

// Round 14
// 2401.833 us; speedup vs baseline: 1.1083x; 1.1083x over previous
//
#include <hip/hip_runtime.h>

constexpr int Bb  = 8;
constexpr int HDn = 256;
constexpr int NQn = 300;
constexpr int NCn = 80;
constexpr int NHn = 8;
constexpr int NPn = 4;
constexpr int Sn  = 8400;
constexpr int MQ  = Bb * NQn;   // 2400
constexpr int MS  = Bb * Sn;    // 67200

typedef __attribute__((ext_vector_type(8))) short short8;
typedef __attribute__((ext_vector_type(4))) float floatx4;

__device__ __forceinline__ unsigned short f2bf(float f) {
    unsigned u = __float_as_uint(f);
    unsigned r = u + 0x7FFFu + ((u >> 16) & 1u);
    return (unsigned short)(r >> 16);
}
__device__ __forceinline__ unsigned pack2(float a, float b) {
    return (unsigned)f2bf(a) | ((unsigned)f2bf(b) << 16);
}

// ======= projection (f32, strided A, K-chunk 32); o-tiles on blockIdx.x =======
__global__ __launch_bounds__(256) void proj_kernel(
    const float* __restrict__ feat, const float* __restrict__ pw,
    const float* __restrict__ bg, const float* __restrict__ bb,
    float* __restrict__ mem,
    int C, int HW, int Wdim, int base)
{
    const int b = blockIdx.z;
    const float* Afeat = feat + (size_t)b * C * HW;
    __shared__ float As[32][128];
    __shared__ float Ws[32][64];
    const int tid = threadIdx.x;
    const int tx = tid & 15, ty = tid >> 4;
    const int p0 = blockIdx.y * 128, o0 = blockIdx.x * 64;
    const int pp4 = (tid & 31) * 4;
    const int cb = tid >> 5;                 // 0..7
    const int wrow = tid & 63, wk = (tid >> 6) * 4;   // 0,4,8,12
    float acc[8][4] = {};
    for (int k0 = 0; k0 < C; k0 += 32) {
        float4 va[4];
#pragma unroll
        for (int c4 = 0; c4 < 4; ++c4) {
            va[c4] = make_float4(0.f, 0.f, 0.f, 0.f);
            if (p0 + pp4 < HW)
                va[c4] = *reinterpret_cast<const float4*>(Afeat + (size_t)(k0 + cb + 8 * c4) * HW + p0 + pp4);
        }
        const float4 vw0 = *reinterpret_cast<const float4*>(pw + (size_t)(o0 + wrow) * C + k0 + wk);
        const float4 vw1 = *reinterpret_cast<const float4*>(pw + (size_t)(o0 + wrow) * C + k0 + wk + 16);
        __syncthreads();
#pragma unroll
        for (int c4 = 0; c4 < 4; ++c4) {
            As[cb + 8 * c4][pp4 + 0] = va[c4].x;
            As[cb + 8 * c4][pp4 + 1] = va[c4].y;
            As[cb + 8 * c4][pp4 + 2] = va[c4].z;
            As[cb + 8 * c4][pp4 + 3] = va[c4].w;
        }
        Ws[wk + 0][wrow] = vw0.x; Ws[wk + 1][wrow] = vw0.y; Ws[wk + 2][wrow] = vw0.z; Ws[wk + 3][wrow] = vw0.w;
        Ws[wk + 16][wrow] = vw1.x; Ws[wk + 17][wrow] = vw1.y; Ws[wk + 18][wrow] = vw1.z; Ws[wk + 19][wrow] = vw1.w;
        __syncthreads();
#pragma unroll
        for (int k = 0; k < 32; ++k) {
            const float4 a0 = *reinterpret_cast<const float4*>(&As[k][ty * 8]);
            const float4 a1 = *reinterpret_cast<const float4*>(&As[k][ty * 8 + 4]);
            const float4 w4 = *reinterpret_cast<const float4*>(&Ws[k][tx * 4]);
            const float av[8] = {a0.x, a0.y, a0.z, a0.w, a1.x, a1.y, a1.z, a1.w};
            const float wv[4] = {w4.x, w4.y, w4.z, w4.w};
#pragma unroll
            for (int i = 0; i < 8; ++i)
#pragma unroll
                for (int j = 0; j < 4; ++j)
                    acc[i][j] = fmaf(av[i], wv[j], acc[i][j]);
        }
    }
#pragma unroll
    for (int i = 0; i < 8; ++i) {
        const int pp = p0 + ty * 8 + i;
        if (pp >= HW) continue;
        const int yy = pp / Wdim, xx = pp - yy * Wdim;
        const float ax = (xx + 0.5f) / Wdim, ay = (yy + 0.5f) / Wdim;
        const float vm = ((ax > 0.01f) && (ax < 0.99f) && (ay > 0.01f) && (ay < 0.99f)) ? 1.f : 0.f;
#pragma unroll
        for (int j = 0; j < 4; ++j) {
            const int o = o0 + tx * 4 + j;
            mem[((size_t)b * Sn + base + pp) * HDn + o] = (acc[i][j] * bg[o] + bb[o]) * vm;
        }
    }
}

// ===== f32 eo GEMM + LayerNorm fused; bank-conflict-free padded Ws; emits bf16(A) side output =====
// Ws physical layout: row k stored as 288 floats, logical col c at phys c + 4*(c>>5).
// Logical mapping & accumulation order identical to unpadded version -> bit-identical output.
__global__ __launch_bounds__(512) void gemm_eoln(
    const float* __restrict__ A,
    const float* __restrict__ W,
    const float* __restrict__ bias,
    const float* __restrict__ g, const float* __restrict__ bt,
    float* __restrict__ O,
    unsigned short* __restrict__ Abf)
{
    __shared__ float As[16][128];
    __shared__ float WsP[16 * 288];
    const int tid = threadIdx.x;
    const int tx = tid & 31;
    const int ty = tid >> 5;
    const int m0 = blockIdx.x * 128;
    const int arow = tid >> 2, ak = (tid & 3) * 4;
    const int wrow = tid >> 1, wk = (tid & 1) * 8;
    const int wphys = wrow + 4 * (wrow >> 5);          // padded column position
    const int rphys = tx * 8 + 4 * (tx >> 2);          // padded read base for cols tx*8..tx*8+7
    float acc[8][8] = {};
    for (int k0 = 0; k0 < 256; k0 += 16) {
        const float4 a4 = *reinterpret_cast<const float4*>(A + (size_t)(m0 + arow) * 256 + k0 + ak);
        const float4 w0 = *reinterpret_cast<const float4*>(W + (size_t)wrow * 256 + k0 + wk);
        const float4 w1 = *reinterpret_cast<const float4*>(W + (size_t)wrow * 256 + k0 + wk + 4);
        if (Abf)
            *reinterpret_cast<uint2*>(Abf + (size_t)(m0 + arow) * 256 + k0 + ak) =
                make_uint2(pack2(a4.x, a4.y), pack2(a4.z, a4.w));
        __syncthreads();
        As[ak + 0][arow] = a4.x; As[ak + 1][arow] = a4.y; As[ak + 2][arow] = a4.z; As[ak + 3][arow] = a4.w;
        WsP[(wk + 0) * 288 + wphys] = w0.x; WsP[(wk + 1) * 288 + wphys] = w0.y;
        WsP[(wk + 2) * 288 + wphys] = w0.z; WsP[(wk + 3) * 288 + wphys] = w0.w;
        WsP[(wk + 4) * 288 + wphys] = w1.x; WsP[(wk + 5) * 288 + wphys] = w1.y;
        WsP[(wk + 6) * 288 + wphys] = w1.z; WsP[(wk + 7) * 288 + wphys] = w1.w;
        __syncthreads();
#pragma unroll
        for (int k = 0; k < 16; ++k) {
            const float4 a0 = *reinterpret_cast<const float4*>(&As[k][ty * 8]);
            const float4 a1 = *reinterpret_cast<const float4*>(&As[k][ty * 8 + 4]);
            const float4 wv0 = *reinterpret_cast<const float4*>(&WsP[k * 288 + rphys]);
            const float4 wv1 = *reinterpret_cast<const float4*>(&WsP[k * 288 + rphys + 4]);
            const float av[8] = {a0.x, a0.y, a0.z, a0.w, a1.x, a1.y, a1.z, a1.w};
            const float wv[8] = {wv0.x, wv0.y, wv0.z, wv0.w, wv1.x, wv1.y, wv1.z, wv1.w};
#pragma unroll
            for (int i = 0; i < 8; ++i)
#pragma unroll
                for (int j = 0; j < 8; ++j)
                    acc[i][j] = fmaf(av[i], wv[j], acc[i][j]);
        }
    }
    float bv[8], gv[8], btv[8];
#pragma unroll
    for (int j = 0; j < 8; ++j) {
        bv[j] = bias[tx * 8 + j];
        gv[j] = g[tx * 8 + j];
        btv[j] = bt[tx * 8 + j];
    }
#pragma unroll
    for (int i = 0; i < 8; ++i) {
        float s1 = 0.f, s2 = 0.f;
#pragma unroll
        for (int j = 0; j < 8; ++j) {
            const float v = acc[i][j] + bv[j];
            acc[i][j] = v;
            s1 += v; s2 += v * v;
        }
#pragma unroll
        for (int o = 1; o < 32; o <<= 1) {
            s1 += __shfl_xor(s1, o, 64);
            s2 += __shfl_xor(s2, o, 64);
        }
        const float mean = s1 * (1.f / 256.f);
        const float var  = s2 * (1.f / 256.f) - mean * mean;
        const float inv  = rsqrtf(var + 1e-5f);
        float out[8];
#pragma unroll
        for (int j = 0; j < 8; ++j) out[j] = (acc[i][j] - mean) * inv * gv[j] + btv[j];
        float* op = O + (size_t)(m0 + ty * 8 + i) * 256 + tx * 8;
        *reinterpret_cast<float4*>(op) = make_float4(out[0], out[1], out[2], out[3]);
        *reinterpret_cast<float4*>(op + 4) = make_float4(out[4], out[5], out[6], out[7]);
    }
}

// ===== f32 es GEMM + row-max fused =====
__global__ __launch_bounds__(256) void gemm_es(
    const float* __restrict__ A,
    const float* __restrict__ W,
    const float* __restrict__ bias,
    float* __restrict__ smax)
{
    __shared__ float As[16][64];
    __shared__ float Ws[16][80];
    const int tid = threadIdx.x;
    const int tx = tid & 15;
    const int ty = tid >> 4;
    const int m0 = blockIdx.x * 64;
    const int arow = tid >> 2, ak = (tid & 3) * 4;
    float acc[4][5] = {};
    for (int k0 = 0; k0 < 256; k0 += 16) {
        const float4 a4 = *reinterpret_cast<const float4*>(A + (size_t)(m0 + arow) * 256 + k0 + ak);
        float4 w0 = make_float4(0.f,0.f,0.f,0.f), w1 = w0;
        const int wrow = tid >> 1, wk = (tid & 1) * 8;
        if (tid < 160) {
            w0 = *reinterpret_cast<const float4*>(W + (size_t)wrow * 256 + k0 + wk);
            w1 = *reinterpret_cast<const float4*>(W + (size_t)wrow * 256 + k0 + wk + 4);
        }
        __syncthreads();
        As[ak + 0][arow] = a4.x; As[ak + 1][arow] = a4.y; As[ak + 2][arow] = a4.z; As[ak + 3][arow] = a4.w;
        if (tid < 160) {
            Ws[wk + 0][wrow] = w0.x; Ws[wk + 1][wrow] = w0.y; Ws[wk + 2][wrow] = w0.z; Ws[wk + 3][wrow] = w0.w;
            Ws[wk + 4][wrow] = w1.x; Ws[wk + 5][wrow] = w1.y; Ws[wk + 6][wrow] = w1.z; Ws[wk + 7][wrow] = w1.w;
        }
        __syncthreads();
#pragma unroll
        for (int k = 0; k < 16; ++k) {
            const float4 a4v = *reinterpret_cast<const float4*>(&As[k][ty * 4]);
            const float av[4] = {a4v.x, a4v.y, a4v.z, a4v.w};
            float wv[5];
#pragma unroll
            for (int j = 0; j < 5; ++j) wv[j] = Ws[k][tx * 5 + j];
#pragma unroll
            for (int i = 0; i < 4; ++i)
#pragma unroll
                for (int j = 0; j < 5; ++j)
                    acc[i][j] = fmaf(av[i], wv[j], acc[i][j]);
        }
    }
    float bv[5];
#pragma unroll
    for (int j = 0; j < 5; ++j) bv[j] = bias[tx * 5 + j];
#pragma unroll
    for (int i = 0; i < 4; ++i) {
        float vmax = -3.0e38f;
#pragma unroll
        for (int j = 0; j < 5; ++j) vmax = fmaxf(vmax, acc[i][j] + bv[j]);
#pragma unroll
        for (int o = 1; o < 16; o <<= 1) vmax = fmaxf(vmax, __shfl_xor(vmax, o, 64));
        if (tx == 0) smax[m0 + ty * 4 + i] = vmax;
    }
}

// ===== f32 -> bf16 convert (fallback path only) =====
__global__ void fconv_kernel(const float* __restrict__ in, unsigned short* __restrict__ out, int n4)
{
    const int i = blockIdx.x * 256 + threadIdx.x;
    if (i >= n4) return;
    const float4 v = reinterpret_cast<const float4*>(in)[i];
    reinterpret_cast<uint2*>(out)[i] = make_uint2(pack2(v.x, v.y), pack2(v.z, v.w));
}

// ===== bf16-A MFMA GEMM 128x256: val = membf @ Wval^T + bias, bf16 out =====
__global__ __launch_bounds__(512) void gemm_vbig(
    const unsigned short* __restrict__ A,
    const float* __restrict__ W,
    const float* __restrict__ bias,
    unsigned short* __restrict__ C, int ldc,
    int M)
{
    __shared__ __align__(16) unsigned short As[128 * 40];
    __shared__ __align__(16) unsigned short Bs[256 * 40];
    const int tid = threadIdx.x;
    const int lane = tid & 63, wid = tid >> 6;
    const int wm = wid >> 2, wn = wid & 3;
    const int m0 = blockIdx.x * 128, n0 = blockIdx.y * 256;
    const int arow = tid >> 2, ak = (tid & 3) * 8;
    const int brow = tid >> 1, bk = (tid & 1) * 16;
    const int fs = (lane >> 4) * 8;
    floatx4 acc[4][4];
#pragma unroll
    for (int i = 0; i < 4; ++i)
#pragma unroll
        for (int j = 0; j < 4; ++j) acc[i][j] = (floatx4){0.f, 0.f, 0.f, 0.f};

    for (int k0 = 0; k0 < 256; k0 += 32) {
        const short8 a8 = *reinterpret_cast<const short8*>(A + (size_t)(m0 + arow) * 256 + k0 + ak);
        float wv[16];
        {
            const float* wp = W + (size_t)(n0 + brow) * 256 + k0 + bk;
#pragma unroll
            for (int j = 0; j < 4; ++j) *reinterpret_cast<float4*>(&wv[4 * j]) = *reinterpret_cast<const float4*>(wp + 4 * j);
        }
        __syncthreads();
        *reinterpret_cast<short8*>(&As[arow * 40 + ak]) = a8;
        *reinterpret_cast<uint4*>(&Bs[brow * 40 + bk]) =
            make_uint4(pack2(wv[0], wv[1]), pack2(wv[2], wv[3]), pack2(wv[4], wv[5]), pack2(wv[6], wv[7]));
        *reinterpret_cast<uint4*>(&Bs[brow * 40 + bk + 8]) =
            make_uint4(pack2(wv[8], wv[9]), pack2(wv[10], wv[11]), pack2(wv[12], wv[13]), pack2(wv[14], wv[15]));
        __syncthreads();
        short8 af[4], bf[4];
#pragma unroll
        for (int mi = 0; mi < 4; ++mi)
            af[mi] = *reinterpret_cast<const short8*>(&As[(wm * 64 + mi * 16 + (lane & 15)) * 40 + fs]);
#pragma unroll
        for (int ni = 0; ni < 4; ++ni)
            bf[ni] = *reinterpret_cast<const short8*>(&Bs[(wn * 64 + ni * 16 + (lane & 15)) * 40 + fs]);
#pragma unroll
        for (int mi = 0; mi < 4; ++mi)
#pragma unroll
            for (int ni = 0; ni < 4; ++ni)
                acc[mi][ni] = __builtin_amdgcn_mfma_f32_16x16x32_bf16(af[mi], bf[ni], acc[mi][ni], 0, 0, 0);
    }
#pragma unroll
    for (int mi = 0; mi < 4; ++mi) {
        const int rowb = m0 + wm * 64 + mi * 16 + (lane >> 4) * 4;
#pragma unroll
        for (int ni = 0; ni < 4; ++ni) {
            const int col = n0 + wn * 64 + ni * 16 + (lane & 15);
            const float bv = bias[col];
#pragma unroll
            for (int r = 0; r < 4; ++r)
                C[(size_t)(rowb + r) * ldc + col] = f2bf(acc[mi][ni][r] + bv);
        }
    }
}

// ===== SMALL bf16 GEMM 64x64, full-K LDS staging; n-tiles on blockIdx.x =====
template <int ACT>
__global__ __launch_bounds__(256) void gemm_sm(
    const float* __restrict__ A, const float* __restrict__ A2, int a2_nlim, int lda,
    const float* __restrict__ W, int ldw,
    const float* __restrict__ bias,
    float* __restrict__ C, int ldc,
    int M, int N, int K)
{
    constexpr int LD = 264;
    __shared__ __align__(16) unsigned short As[64 * LD];
    __shared__ __align__(16) unsigned short Bs[64 * LD];
    const int tid = threadIdx.x;
    const int lane = tid & 63, wid = tid >> 6;
    const int wr = wid >> 1, wc = wid & 1;
    const int m0 = blockIdx.y * 64, n0 = blockIdx.x * 64;
    const float* A2e = (A2 && n0 < a2_nlim) ? A2 : nullptr;
    const int srow = tid >> 2;
    const int cb   = (tid & 3) * 16;
    const int fs = (lane >> 4) * 8;
    floatx4 acc[2][2];
#pragma unroll
    for (int i = 0; i < 2; ++i)
#pragma unroll
        for (int j = 0; j < 2; ++j) acc[i][j] = (floatx4){0.f, 0.f, 0.f, 0.f};

    for (int kc = 0; kc < K; kc += 256) {
        if (kc) __syncthreads();
        {
            const bool mok = (m0 + srow < M);
            const float* ap = A + (size_t)(m0 + srow) * lda + kc;
            const float* ap2 = A2e ? A2e + (size_t)(m0 + srow) * lda + kc : nullptr;
#pragma unroll
            for (int c = 0; c < 4; ++c) {
                float4 v[4];
#pragma unroll
                for (int j = 0; j < 4; ++j) {
                    v[j] = make_float4(0.f, 0.f, 0.f, 0.f);
                    if (mok) {
                        v[j] = *reinterpret_cast<const float4*>(ap + cb + c * 64 + j * 4);
                        if (ap2) {
                            const float4 v2 = *reinterpret_cast<const float4*>(ap2 + cb + c * 64 + j * 4);
                            v[j].x += v2.x; v[j].y += v2.y; v[j].z += v2.z; v[j].w += v2.w;
                        }
                    }
                }
#pragma unroll
                for (int j = 0; j < 4; ++j)
                    *reinterpret_cast<uint2*>(&As[srow * LD + cb + c * 64 + j * 4]) =
                        make_uint2(pack2(v[j].x, v[j].y), pack2(v[j].z, v[j].w));
            }
        }
        {
            const bool nok = (n0 + srow < N);
            const float* wp = W + (size_t)(n0 + srow) * ldw + kc;
#pragma unroll
            for (int c = 0; c < 4; ++c) {
                float4 v[4];
#pragma unroll
                for (int j = 0; j < 4; ++j) {
                    v[j] = make_float4(0.f, 0.f, 0.f, 0.f);
                    if (nok) v[j] = *reinterpret_cast<const float4*>(wp + cb + c * 64 + j * 4);
                }
#pragma unroll
                for (int j = 0; j < 4; ++j)
                    *reinterpret_cast<uint2*>(&Bs[srow * LD + cb + c * 64 + j * 4]) =
                        make_uint2(pack2(v[j].x, v[j].y), pack2(v[j].z, v[j].w));
            }
        }
        __syncthreads();
#pragma unroll
        for (int ks = 0; ks < 8; ++ks) {
            short8 af[2], bf[2];
#pragma unroll
            for (int mi = 0; mi < 2; ++mi)
                af[mi] = *reinterpret_cast<const short8*>(&As[(wr * 32 + mi * 16 + (lane & 15)) * LD + ks * 32 + fs]);
#pragma unroll
            for (int ni = 0; ni < 2; ++ni)
                bf[ni] = *reinterpret_cast<const short8*>(&Bs[(wc * 32 + ni * 16 + (lane & 15)) * LD + ks * 32 + fs]);
#pragma unroll
            for (int mi = 0; mi < 2; ++mi)
#pragma unroll
                for (int ni = 0; ni < 2; ++ni)
                    acc[mi][ni] = __builtin_amdgcn_mfma_f32_16x16x32_bf16(af[mi], bf[ni], acc[mi][ni], 0, 0, 0);
        }
    }
#pragma unroll
    for (int mi = 0; mi < 2; ++mi) {
        const int rowb = m0 + wr * 32 + mi * 16 + (lane >> 4) * 4;
#pragma unroll
        for (int ni = 0; ni < 2; ++ni) {
            const int col = n0 + wc * 32 + ni * 16 + (lane & 15);
            if (col >= N) continue;
            const float bv = bias[col];
#pragma unroll
            for (int r = 0; r < 4; ++r) {
                const int row = rowb + r;
                if (row >= M) continue;
                float v = acc[mi][ni][r] + bv;
                if (ACT == 1) v = fmaxf(v, 0.f);
                C[(size_t)row * ldc + col] = v;
            }
        }
    }
}

// ============== qpos: C = (relu(ref @ w1^T + b1)) @ w2^T + b2 ==============
__global__ __launch_bounds__(256) void gemm_qpos(
    const float* __restrict__ ref, const float* __restrict__ w1, const float* __restrict__ b1,
    const float* __restrict__ W2, const float* __restrict__ b2,
    float* __restrict__ C, int M)
{
    __shared__ __align__(16) unsigned short As_h[128 * 40];
    __shared__ __align__(16) unsigned short Bs_h[128 * 40];
    __shared__ float w1s[512 * 4];
    __shared__ float b1s[512];
    const int tid = threadIdx.x;
    const int lane = tid & 63, wid = tid >> 6;
    const int wm = wid >> 1, wn = wid & 1;
    const int m0 = blockIdx.x * 128, n0 = blockIdx.y * 128;
    const int srow = tid >> 1, skoff = (tid & 1) * 16;
    const int fs = (lane >> 4) * 8;
    for (int i = tid; i < 512 * 4; i += 256) w1s[i] = w1[i];
    for (int i = tid; i < 512; i += 256) b1s[i] = b1[i];
    float rv0 = 0.f, rv1 = 0.f, rv2 = 0.f, rv3 = 0.f;
    if (m0 + srow < M) {
        const float* rp = ref + (size_t)(m0 + srow) * 4;
        rv0 = rp[0]; rv1 = rp[1]; rv2 = rp[2]; rv3 = rp[3];
    }
    floatx4 acc[4][4];
#pragma unroll
    for (int i = 0; i < 4; ++i)
#pragma unroll
        for (int j = 0; j < 4; ++j) acc[i][j] = (floatx4){0.f, 0.f, 0.f, 0.f};
    __syncthreads();

    for (int k0 = 0; k0 < 512; k0 += 32) {
        float av[16], wv[16];
#pragma unroll
        for (int j = 0; j < 16; ++j) {
            const int k = k0 + skoff + j;
            const float v = b1s[k] + rv0 * w1s[k * 4] + rv1 * w1s[k * 4 + 1] + rv2 * w1s[k * 4 + 2] + rv3 * w1s[k * 4 + 3];
            av[j] = fmaxf(v, 0.f);
            wv[j] = 0.f;
        }
        if (n0 + srow < 256) {
            const float* wp = W2 + (size_t)(n0 + srow) * 512 + k0 + skoff;
#pragma unroll
            for (int j = 0; j < 4; ++j) *reinterpret_cast<float4*>(&wv[4 * j]) = *reinterpret_cast<const float4*>(wp + 4 * j);
        }
        __syncthreads();
        *reinterpret_cast<uint4*>(&As_h[srow * 40 + skoff]) =
            make_uint4(pack2(av[0], av[1]), pack2(av[2], av[3]), pack2(av[4], av[5]), pack2(av[6], av[7]));
        *reinterpret_cast<uint4*>(&As_h[srow * 40 + skoff + 8]) =
            make_uint4(pack2(av[8], av[9]), pack2(av[10], av[11]), pack2(av[12], av[13]), pack2(av[14], av[15]));
        *reinterpret_cast<uint4*>(&Bs_h[srow * 40 + skoff]) =
            make_uint4(pack2(wv[0], wv[1]), pack2(wv[2], wv[3]), pack2(wv[4], wv[5]), pack2(wv[6], wv[7]));
        *reinterpret_cast<uint4*>(&Bs_h[srow * 40 + skoff + 8]) =
            make_uint4(pack2(wv[8], wv[9]), pack2(wv[10], wv[11]), pack2(wv[12], wv[13]), pack2(wv[14], wv[15]));
        __syncthreads();
        short8 af[4], bff[4];
#pragma unroll
        for (int mi = 0; mi < 4; ++mi) {
            const int r = wm * 64 + mi * 16 + (lane & 15);
            af[mi] = *reinterpret_cast<const short8*>(&As_h[r * 40 + fs]);
        }
#pragma unroll
        for (int ni = 0; ni < 4; ++ni) {
            const int r = wn * 64 + ni * 16 + (lane & 15);
            bff[ni] = *reinterpret_cast<const short8*>(&Bs_h[r * 40 + fs]);
        }
#pragma unroll
        for (int mi = 0; mi < 4; ++mi)
#pragma unroll
            for (int ni = 0; ni < 4; ++ni)
                acc[mi][ni] = __builtin_amdgcn_mfma_f32_16x16x32_bf16(af[mi], bff[ni], acc[mi][ni], 0, 0, 0);
    }
#pragma unroll
    for (int mi = 0; mi < 4; ++mi) {
        const int rowb = m0 + wm * 64 + mi * 16 + (lane >> 4) * 4;
#pragma unroll
        for (int ni = 0; ni < 4; ++ni) {
            const int col = n0 + wn * 64 + ni * 16 + (lane & 15);
            const float bv = b2[col];
#pragma unroll
            for (int r = 0; r < 4; ++r) {
                const int row = rowb + r;
                if (row >= M) continue;
                C[(size_t)row * HDn + col] = acc[mi][ni][r] + bv;
            }
        }
    }
}

// ================= LayerNorm over rows of 256 with residual =================
__global__ __launch_bounds__(256) void ln_kernel(
    const float* __restrict__ X, const float* __restrict__ R,
    const float* __restrict__ g, const float* __restrict__ bta,
    float* __restrict__ O)
{
    const int m = blockIdx.x;
    const int t = threadIdx.x;
    float v = X[(size_t)m * HDn + t] + R[(size_t)m * HDn + t];
    float s1 = v, s2 = v * v;
#pragma unroll
    for (int o = 32; o > 0; o >>= 1) {
        s1 += __shfl_down(s1, o, 64);
        s2 += __shfl_down(s2, o, 64);
    }
    __shared__ float a1[4], a2[4];
    if ((t & 63) == 0) { a1[t >> 6] = s1; a2[t >> 6] = s2; }
    __syncthreads();
    const float S1 = a1[0] + a1[1] + a1[2] + a1[3];
    const float S2 = a2[0] + a2[1] + a2[2] + a2[3];
    const float mean = S1 * (1.f / HDn);
    const float var  = S2 * (1.f / HDn) - mean * mean;
    const float inv  = rsqrtf(var + 1e-5f);
    O[(size_t)m * HDn + t] = (v - mean) * inv * g[t] + bta[t];
}

// ===== top-300 per batch via MSB radix select =====
__global__ __launch_bounds__(256) void topk_kernel(const float* __restrict__ smax, int* __restrict__ topi)
{
    const int b = blockIdx.x, t = threadIdx.x;
    __shared__ float vals[Sn];
    __shared__ int hist[256];
    __shared__ unsigned long long sel[NQn];
    __shared__ unsigned long long s_prefix;
    __shared__ int s_need;
    __shared__ int s_cnt;
    for (int i = t; i < Sn; i += 256) vals[i] = smax[(size_t)b * Sn + i];
    if (t == 0) { s_prefix = 0ULL; s_need = NQn; s_cnt = 0; }
    __syncthreads();

    for (int shift = 56; shift >= 0; shift -= 8) {
        if (t < 256) hist[t] = 0;
        __syncthreads();
        const unsigned long long prefix = s_prefix;
        const unsigned long long mask = (shift == 56) ? 0ULL : (~0ULL << (shift + 8));
        for (int i = t; i < Sn; i += 256) {
            unsigned uk = __float_as_uint(vals[i]);
            uk = (uk & 0x80000000u) ? ~uk : (uk | 0x80000000u);
            const unsigned long long key = ((unsigned long long)uk << 32) | (unsigned)(Sn - i);
            if ((key & mask) == prefix)
                atomicAdd(&hist[(int)((key >> shift) & 255)], 1);
        }
        __syncthreads();
        if (t == 0) {
            int need = s_need, accum = 0, v = 255;
            for (; v >= 0; --v) {
                const int c = hist[v];
                if (accum + c >= need) break;
                accum += c;
            }
            s_prefix = s_prefix | ((unsigned long long)(unsigned)v << shift);
            s_need = need - accum;
        }
        __syncthreads();
    }
    const unsigned long long thresh = s_prefix;
    for (int i = t; i < Sn; i += 256) {
        unsigned uk = __float_as_uint(vals[i]);
        uk = (uk & 0x80000000u) ? ~uk : (uk | 0x80000000u);
        const unsigned long long key = ((unsigned long long)uk << 32) | (unsigned)(Sn - i);
        if (key >= thresh) {
            const int pos = atomicAdd(&s_cnt, 1);
            if (pos < NQn) sel[pos] = key;
        }
    }
    __syncthreads();
    for (int j = t; j < NQn; j += 256) {
        const unsigned long long kj = sel[j];
        int rank = 0;
        for (int i = 0; i < NQn; ++i) rank += (sel[i] > kj) ? 1 : 0;
        topi[b * NQn + rank] = Sn - (int)(kj & 0xFFFFFFFFULL);
    }
}

// ================= gather selected rows =================
__global__ __launch_bounds__(256) void gather_kernel(const float* __restrict__ src, const int* __restrict__ topi,
                                                     float* __restrict__ dst)
{
    const int m = blockIdx.x;
    const int b = m / NQn;
    const int s = topi[m];
    dst[(size_t)m * HDn + threadIdx.x] = src[((size_t)b * Sn + s) * HDn + threadIdx.x];
}

// ================= anchors =================
__device__ __forceinline__ void anchor_of(int s, float a[4])
{
    int lvl, p, w;
    if (s < 6400)      { lvl = 0; p = s;        w = 80; }
    else if (s < 8000) { lvl = 1; p = s - 6400; w = 40; }
    else               { lvl = 2; p = s - 8000; w = 20; }
    const int y = p / w, x = p - y * w;
    const float ax = (x + 0.5f) / w, ay = (y + 0.5f) / w;
    const float awh = 0.05f * (float)(1 << lvl);
    const bool valid = (ax > 0.01f) && (ax < 0.99f) && (ay > 0.01f) && (ay < 0.99f);
    if (valid) {
        a[0] = logf(ax / (1.f - ax));
        a[1] = logf(ay / (1.f - ay));
        const float lw = logf(awh / (1.f - awh));
        a[2] = lw; a[3] = lw;
    } else {
        a[0] = a[1] = a[2] = a[3] = 1e6f;
    }
}

// ===== fused N=4 head + ref update; optionally mirrors ref into out[84-stride] rows =====
template <int MODE>
__global__ __launch_bounds__(256) void head4_kernel(
    const float* __restrict__ A, const float* __restrict__ W, const float* __restrict__ bias,
    const int* __restrict__ topi, float* __restrict__ ref, float* __restrict__ outref)
{
    const int wv = threadIdx.x >> 6, lane = threadIdx.x & 63;
    const int m = blockIdx.x * 4 + wv;
    if (m >= MQ) return;
    const float4 a = *reinterpret_cast<const float4*>(A + (size_t)m * HDn + lane * 4);
    float d[4];
#pragma unroll
    for (int c = 0; c < 4; ++c) {
        const float4 w = *reinterpret_cast<const float4*>(W + c * HDn + lane * 4);
        float p = a.x * w.x + a.y * w.y + a.z * w.z + a.w * w.w;
#pragma unroll
        for (int o = 32; o > 0; o >>= 1) p += __shfl_xor(p, o, 64);
        d[c] = p;
    }
    if (lane == 0) {
        float base[4];
        if (MODE == 0) {
            anchor_of(topi[m], base);
        } else {
#pragma unroll
            for (int c = 0; c < 4; ++c) {
                float x = ref[m * 4 + c];
                x = fminf(fmaxf(x, 0.f), 1.f);
                base[c] = logf(fmaxf(x, 1e-5f) / fmaxf(1.f - x, 1e-5f));
            }
        }
#pragma unroll
        for (int c = 0; c < 4; ++c) {
            const float x = d[c] + bias[c] + base[c];
            const float r = 1.f / (1.f + expf(-x));
            ref[m * 4 + c] = r;
            if (outref) outref[(size_t)m * 84 + 80 + c] = r;
        }
    }
}

// ===== fused MHA: q-split across blocks (z), k-split within block =====
__global__ __launch_bounds__(320) void mha_kernel(const float* __restrict__ QKV, float* __restrict__ O)
{
    const int h = blockIdx.x, b = blockIdx.y, qs = blockIdx.z;
    __shared__ float Ks[NQn][32];
    __shared__ float Vs[NQn][32];
    __shared__ float Om[152][32];
    __shared__ float Mm[152];
    __shared__ float Lm[152];
    const int t = threadIdx.x;
    for (int i = t; i < NQn * 32; i += 320) {
        const int kk = i >> 5, d = i & 31;
        const size_t src = ((size_t)(b * NQn + kk)) * 768 + h * 32 + d;
        Ks[kk][d] = QKV[src + 256];
        Vs[kk][d] = QKV[src + 512];
    }
    __syncthreads();
    const int half = (t >= 160) ? 1 : 0;
    const int qloc = half ? (t - 160) : t;
    const int q = qs * 150 + qloc;
    float m = -1e30f, l = 0.f;
    float o[32];
    if (qloc < 150) {
        float qv[32];
        const float* qp = QKV + ((size_t)(b * NQn + q)) * 768 + h * 32;
#pragma unroll
        for (int d = 0; d < 32; ++d) qv[d] = qp[d] * 0.17677669529663687f;
#pragma unroll
        for (int d = 0; d < 32; ++d) o[d] = 0.f;
        const int k0 = half * 150, k1 = k0 + 150;
        for (int kk = k0; kk < k1; ++kk) {
            float s0 = 0.f, s1 = 0.f, s2 = 0.f, s3 = 0.f;
#pragma unroll
            for (int d = 0; d < 32; d += 4) {
                s0 = fmaf(qv[d + 0], Ks[kk][d + 0], s0);
                s1 = fmaf(qv[d + 1], Ks[kk][d + 1], s1);
                s2 = fmaf(qv[d + 2], Ks[kk][d + 2], s2);
                s3 = fmaf(qv[d + 3], Ks[kk][d + 3], s3);
            }
            const float s = (s0 + s1) + (s2 + s3);
            if (s > m + 8.f) {
                const float cf = __expf(m - s);
                m = s;
                l *= cf;
#pragma unroll
                for (int d = 0; d < 32; ++d) o[d] *= cf;
            }
            const float pv = __expf(s - m);
            l += pv;
#pragma unroll
            for (int d = 0; d < 32; ++d) o[d] = fmaf(pv, Vs[kk][d], o[d]);
        }
        if (half) {
            Mm[qloc] = m; Lm[qloc] = l;
#pragma unroll
            for (int d = 0; d < 32; ++d) Om[qloc][d] = o[d];
        }
    }
    __syncthreads();
    if (!half && qloc < 150) {
        const float m2 = Mm[qloc], l2 = Lm[qloc];
        const float mm = fmaxf(m, m2);
        const float c1 = __expf(m - mm), c2 = __expf(m2 - mm);
        const float L = l * c1 + l2 * c2;
        const float inv = 1.f / L;
        float* op = O + ((size_t)(b * NQn + q)) * HDn + h * 32;
#pragma unroll
        for (int d = 0; d < 32; ++d) op[d] = (o[d] * c1 + Om[qloc][d] * c2) * inv;
    }
}

// ====== concat off/aw weights+biases once ======
__global__ void concat_oaw(const float* __restrict__ offw, const float* __restrict__ offbias,
                           const float* __restrict__ aww, const float* __restrict__ awbias,
                           float* __restrict__ cw, float* __restrict__ cb)
{
    const int idx = blockIdx.x * 256 + threadIdx.x;
    const int TW = 6 * 288 * 256;
    if (idx < TW) {
        const int i = idx / (288 * 256);
        const int r = (idx / 256) % 288;
        const int c = idx & 255;
        cw[idx] = (r < 192) ? offw[((size_t)i * 192 + r) * 256 + c]
                            : aww[((size_t)i * 96 + (r - 192)) * 256 + c];
    } else if (idx < TW + 6 * 288) {
        const int j = idx - TW;
        const int i = j / 288, r = j % 288;
        cb[j] = (r < 192) ? offbias[i * 192 + r] : awbias[i * 96 + (r - 192)];
    }
}

// ============ deformable attention sampling (bf16 value tensor), softmax12 fused ============
__global__ __launch_bounds__(256) void msda_kernel(const unsigned short* __restrict__ val, int ldv,
                                                   const float* __restrict__ oaw,
                                                   const float* __restrict__ ref,
                                                   float* __restrict__ out)
{
    const int mq = blockIdx.x;
    const int b = mq / NQn;
    const int t = threadIdx.x;
    const int h = t >> 5, d = t & 31;
    __shared__ float s_ref[4];
    __shared__ float s_aw[96];
    __shared__ float s_off[192];
    if (t < 4) s_ref[t] = ref[mq * 4 + t];
    if (t < 96) s_aw[t] = oaw[(size_t)mq * 288 + 192 + t];
    if (t < 192) s_off[t] = oaw[(size_t)mq * 288 + t];
    __syncthreads();
    if (t < 8) {
        float* p = s_aw + t * 12;
        float mx = -1e30f;
#pragma unroll
        for (int i = 0; i < 12; ++i) mx = fmaxf(mx, p[i]);
        float e[12];
        float s = 0.f;
#pragma unroll
        for (int i = 0; i < 12; ++i) { e[i] = expf(p[i] - mx); s += e[i]; }
        const float inv = 1.f / s;
#pragma unroll
        for (int i = 0; i < 12; ++i) p[i] = e[i] * inv;
    }
    __syncthreads();
    const int Wl[3] = {80, 40, 20};
    const int base[3] = {0, 6400, 8000};
    float acc = 0.f;
#pragma unroll
    for (int l = 0; l < 3; ++l) {
        const int W = Wl[l];
        const unsigned short* vb = val + ((size_t)b * Sn + base[l]) * ldv + h * 32 + d;
#pragma unroll
        for (int p = 0; p < 4; ++p) {
            const float ox = s_off[((h * 3 + l) * 4 + p) * 2 + 0];
            const float oy = s_off[((h * 3 + l) * 4 + p) * 2 + 1];
            const float locx = s_ref[0] + ox * (1.f / NPn) * s_ref[2] * 0.5f;
            const float locy = s_ref[1] + oy * (1.f / NPn) * s_ref[3] * 0.5f;
            const float x = locx * W - 0.5f;
            const float y = locy * W - 0.5f;
            const float x0f = floorf(x), y0f = floorf(y);
            const float lx = x - x0f, ly = y - y0f;
            const int x0 = (int)x0f, y0 = (int)y0f;
            const float a = s_aw[h * 12 + l * 4 + p];
            const float wts[4] = {(1.f - lx) * (1.f - ly), lx * (1.f - ly), (1.f - lx) * ly, lx * ly};
            float sum = 0.f;
#pragma unroll
            for (int c2 = 0; c2 < 4; ++c2) {
                const int xi = x0 + (c2 & 1);
                const int yi = y0 + (c2 >> 1);
                const bool ok = (xi >= 0) && (xi < W) && (yi >= 0) && (yi < W);
                const int xc = min(max(xi, 0), W - 1);
                const int yc = min(max(yi, 0), W - 1);
                const float v = __uint_as_float((unsigned)vb[(size_t)(yc * W + xc) * ldv] << 16);
                sum = fmaf(wts[c2], ok ? v : 0.f, sum);
            }
            acc = fmaf(a, sum, acc);
        }
    }
    out[(size_t)mq * HDn + t] = acc;
}

// =======================================================================================
extern "C" void kernel_launch(void* const* d_in, const int* in_sizes, int n_in,
                              void* d_out, int out_size, void* d_ws, size_t ws_size,
                              hipStream_t stream)
{
    (void)in_sizes; (void)n_in; (void)out_size;
    const float* feat0 = (const float*)d_in[0];
    const float* pw0   = (const float*)d_in[1];
    const float* bg0   = (const float*)d_in[2];
    const float* bb0   = (const float*)d_in[3];
    const float* feat1 = (const float*)d_in[4];
    const float* pw1   = (const float*)d_in[5];
    const float* bg1   = (const float*)d_in[6];
    const float* bb1   = (const float*)d_in[7];
    const float* feat2 = (const float*)d_in[8];
    const float* pw2   = (const float*)d_in[9];
    const float* bg2   = (const float*)d_in[10];
    const float* bb2   = (const float*)d_in[11];
    const float* eo_w  = (const float*)d_in[12];
    const float* eo_b  = (const float*)d_in[13];
    const float* eln_g = (const float*)d_in[14];
    const float* eln_b = (const float*)d_in[15];
    const float* es_w  = (const float*)d_in[16];
    const float* es_b  = (const float*)d_in[17];
    const float* eb_w1 = (const float*)d_in[18];
    const float* eb_b1 = (const float*)d_in[19];
    const float* eb_w2 = (const float*)d_in[20];
    const float* eb_b2 = (const float*)d_in[21];
    const float* eb_w3 = (const float*)d_in[22];
    const float* eb_b3 = (const float*)d_in[23];
    const float* qp_w1 = (const float*)d_in[24];
    const float* qp_b1 = (const float*)d_in[25];
    const float* qp_w2 = (const float*)d_in[26];
    const float* qp_b2 = (const float*)d_in[27];
    const float* d_qkv_w = (const float*)d_in[28];
    const float* d_qkv_b = (const float*)d_in[29];
    const float* d_ao_w  = (const float*)d_in[30];
    const float* d_ao_b  = (const float*)d_in[31];
    const float* d_ln1_g = (const float*)d_in[32];
    const float* d_ln1_b = (const float*)d_in[33];
    const float* d_off_w = (const float*)d_in[34];
    const float* d_off_b = (const float*)d_in[35];
    const float* d_aw_w  = (const float*)d_in[36];
    const float* d_aw_b  = (const float*)d_in[37];
    const float* d_val_w = (const float*)d_in[38];
    const float* d_val_b = (const float*)d_in[39];
    const float* d_out_w = (const float*)d_in[40];
    const float* d_out_b = (const float*)d_in[41];
    const float* d_ln2_g = (const float*)d_in[42];
    const float* d_ln2_b = (const float*)d_in[43];
    const float* d_f1_w  = (const float*)d_in[44];
    const float* d_f1_b  = (const float*)d_in[45];
    const float* d_f2_w  = (const float*)d_in[46];
    const float* d_f2_b  = (const float*)d_in[47];
    const float* d_ln3_g = (const float*)d_in[48];
    const float* d_ln3_b = (const float*)d_in[49];
    const float* d_sc_w  = (const float*)d_in[50];
    const float* d_sc_b  = (const float*)d_in[51];
    const float* d_bb_w1 = (const float*)d_in[52];
    const float* d_bb_b1 = (const float*)d_in[53];
    const float* d_bb_w2 = (const float*)d_in[54];
    const float* d_bb_b2 = (const float*)d_in[55];
    const float* d_bb_w3 = (const float*)d_in[56];
    const float* d_bb_b3 = (const float*)d_in[57];

    float* ws = (float*)d_ws;
    size_t off = 0;
    auto alloc = [&](size_t n) { float* p = ws + off; off += (n + 63) & ~(size_t)63; return p; };
    float* memory = alloc((size_t)MS * HDn);
    float* om     = alloc((size_t)MS * HDn);
    float* smaxb  = alloc((size_t)MS);
    int*   topi   = (int*)alloc((size_t)MQ);
    float* tgt    = alloc((size_t)MQ * HDn);
    float* refb   = alloc((size_t)MQ * 4);
    float* qpos   = alloc((size_t)MQ * HDn);
    float* qkvb   = alloc((size_t)MQ * 768);
    float* atto   = alloc((size_t)MQ * HDn);
    float* abuf   = alloc((size_t)MQ * HDn);
    float* oawb   = alloc((size_t)MQ * 288);
    float* msd    = alloc((size_t)MQ * HDn);
    float* ffb    = alloc((size_t)MQ * 1024);
    float* qb     = alloc((size_t)MQ * HDn);
    float* kb     = alloc((size_t)MQ * HDn);
    float* cw     = alloc((size_t)6 * 288 * 256);
    float* cb     = alloc((size_t)6 * 288);
    const size_t VALBIG_FLOATS = (size_t)MS * 768;   // [MS][1536] bf16
    const size_t MEMBF_FLOATS  = (size_t)MS * 128;   // [MS][256] bf16
    unsigned short* valbig = nullptr;
    unsigned short* membf  = nullptr;
    if ((off + VALBIG_FLOATS + MEMBF_FLOATS + 128) * sizeof(float) <= ws_size) {
        valbig = (unsigned short*)alloc(VALBIG_FLOATS);
        membf  = (unsigned short*)alloc(MEMBF_FLOATS);
    }
    const bool batched = (valbig != nullptr);
    unsigned short* ombf = (unsigned short*)om;   // fallback path scratch
    float* outp = (float*)d_out;

    // ---- weight concat for merged off+aw GEMM ----
    concat_oaw<<<(6 * 288 * 256 + 6 * 288 + 255) / 256, 256, 0, stream>>>(d_off_w, d_off_b, d_aw_w, d_aw_b, cw, cb);

    // ---- stage 1: projection (f32 — selection-critical score path) ----
    proj_kernel<<<dim3(4, 50, 8), 256, 0, stream>>>(feat0, pw0, bg0, bb0, memory, 512, 6400, 80, 0);
    proj_kernel<<<dim3(4, 13, 8), 256, 0, stream>>>(feat1, pw1, bg1, bb1, memory, 1024, 1600, 40, 6400);
    proj_kernel<<<dim3(4, 4, 8), 256, 0, stream>>>(feat2, pw2, bg2, bb2, memory, 2048, 400, 20, 8000);

    // ---- stage 2: encoder head (f32, fused); eoln also emits bf16(memory) ----
    gemm_eoln<<<525, 512, 0, stream>>>(memory, eo_w, eo_b, eln_g, eln_b, om, batched ? membf : nullptr);
    gemm_es<<<1050, 256, 0, stream>>>(om, es_w, es_b, smaxb);
    topk_kernel<<<Bb, 256, 0, stream>>>(smaxb, topi);
    gather_kernel<<<MQ, 256, 0, stream>>>(om, topi, tgt);

    // ---- ref init ----
    gemm_sm<1><<<dim3(4, 38), 256, 0, stream>>>(tgt, nullptr, 0, HDn, eb_w1, HDn, eb_b1, qb, HDn, MQ, HDn, HDn);
    gemm_sm<1><<<dim3(4, 38), 256, 0, stream>>>(qb, nullptr, 0, HDn, eb_w2, HDn, eb_b2, kb, HDn, MQ, HDn, HDn);
    head4_kernel<0><<<600, 256, 0, stream>>>(kb, eb_w3, eb_b3, topi, refb, nullptr);

    // ---- all 6 layers' value projections: one wide bf16 GEMM on membf ----
    if (batched)
        gemm_vbig<<<dim3(525, 6), 512, 0, stream>>>(membf, d_val_w, d_val_b, valbig, 1536, MS);

    // ---- decoder layers ----
    for (int i = 0; i < 6; ++i) {
        const float* wqkv = d_qkv_w + (size_t)i * 768 * 256;
        const float* bqkv = d_qkv_b + (size_t)i * 768;
        gemm_qpos<<<dim3(19, 2), 256, 0, stream>>>(refb, qp_w1, qp_b1, qp_w2, qp_b2, qpos, MQ);
        gemm_sm<0><<<dim3(12, 38), 256, 0, stream>>>(tgt, qpos, 512, HDn, wqkv, HDn, bqkv, qkvb, 768, MQ, 768, HDn);
        mha_kernel<<<dim3(NHn, Bb, 2), 320, 0, stream>>>(qkvb, atto);
        gemm_sm<0><<<dim3(4, 38), 256, 0, stream>>>(atto, nullptr, 0, HDn, d_ao_w + (size_t)i * 65536, HDn,
                                                    d_ao_b + (size_t)i * 256, abuf, HDn, MQ, HDn, HDn);
        ln_kernel<<<MQ, 256, 0, stream>>>(abuf, tgt, d_ln1_g + (size_t)i * 256, d_ln1_b + (size_t)i * 256, tgt);
        gemm_sm<0><<<dim3(5, 38), 256, 0, stream>>>(tgt, qpos, 1 << 30, HDn, cw + (size_t)i * 288 * 256, HDn,
                                                    cb + (size_t)i * 288, oawb, 288, MQ, 288, HDn);
        const unsigned short* valptr;
        int ldv;
        if (batched) { valptr = valbig + (size_t)i * 256; ldv = 1536; }
        else {
            fconv_kernel<<<(MS * HDn / 4 + 255) / 256, 256, 0, stream>>>(memory, (unsigned short*)ffb, MS * HDn / 4);
            gemm_vbig<<<dim3(525, 1), 512, 0, stream>>>((unsigned short*)ffb, d_val_w + (size_t)i * 65536,
                                                        d_val_b + (size_t)i * 256, ombf, 256, MS);
            valptr = ombf; ldv = 256;
        }
        msda_kernel<<<MQ, 256, 0, stream>>>(valptr, ldv, oawb, refb, msd);
        gemm_sm<0><<<dim3(4, 38), 256, 0, stream>>>(msd, nullptr, 0, HDn, d_out_w + (size_t)i * 65536, HDn,
                                                    d_out_b + (size_t)i * 256, abuf, HDn, MQ, HDn, HDn);
        ln_kernel<<<MQ, 256, 0, stream>>>(abuf, tgt, d_ln2_g + (size_t)i * 256, d_ln2_b + (size_t)i * 256, tgt);
        gemm_sm<1><<<dim3(16, 38), 256, 0, stream>>>(tgt, nullptr, 0, HDn, d_f1_w + (size_t)i * 1024 * 256, HDn,
                                                     d_f1_b + (size_t)i * 1024, ffb, 1024, MQ, 1024, HDn);
        gemm_sm<0><<<dim3(4, 38), 256, 0, stream>>>(ffb, nullptr, 0, 1024, d_f2_w + (size_t)i * 256 * 1024, 1024,
                                                    d_f2_b + (size_t)i * 256, abuf, HDn, MQ, HDn, 1024);
        ln_kernel<<<MQ, 256, 0, stream>>>(abuf, tgt, d_ln3_g + (size_t)i * 256, d_ln3_b + (size_t)i * 256, tgt);
        gemm_sm<1><<<dim3(4, 38), 256, 0, stream>>>(tgt, nullptr, 0, HDn, d_bb_w1 + (size_t)i * 65536, HDn,
                                                    d_bb_b1 + (size_t)i * 256, qb, HDn, MQ, HDn, HDn);
        gemm_sm<1><<<dim3(4, 38), 256, 0, stream>>>(qb, nullptr, 0, HDn, d_bb_w2 + (size_t)i * 65536, HDn,
                                                    d_bb_b2 + (size_t)i * 256, kb, HDn, MQ, HDn, HDn);
        head4_kernel<1><<<600, 256, 0, stream>>>(kb, d_bb_w3 + (size_t)i * 1024, d_bb_b3 + (size_t)i * 4,
                                                 nullptr, refb, (i == 5) ? outp : nullptr);
    }

    // ---- final logits head into d_out: [logits(80) | ref(4)] per (b,q) ----
    gemm_sm<0><<<dim3(2, 38), 256, 0, stream>>>(tgt, nullptr, 0, HDn, d_sc_w + (size_t)5 * 80 * 256, HDn,
                                                d_sc_b + (size_t)5 * 80, outp, 84, MQ, NCn, HDn);
}